// Round 6
// baseline (1526.137 us; speedup 1.0000x reference)
//
#include <hip/hip_runtime.h>

#define L_SEQ 1024
#define NB 32
#define NH 8
#define NE 64
#define TOPK 6
#define RS 1089   // LDS row stride: 1024 + 64 (pad every 16) + 1 (odd stride for bank spread)

// physical offset of point p within a padded LDS row: contiguous 16-groups at stride 17
__device__ __forceinline__ int physp(int p) { return 17 * (p >> 4) + (p & 15); }

// ---- base-twiddle table: W_64^j = (cos(pi j/32), sin(pi j/32)), j = 0..31 ----
// runtime lane-indexed (L1-cached global); sign applied per direction.
__device__ const float TW64C[32] = {
    1.000000000f, 0.995184727f, 0.980785280f, 0.956940336f,
    0.923879533f, 0.881921264f, 0.831469612f, 0.773010453f,
    0.707106781f, 0.634393284f, 0.555570233f, 0.471396737f,
    0.382683432f, 0.290284677f, 0.195090322f, 0.098017140f,
    0.000000000f,-0.098017140f,-0.195090322f,-0.290284677f,
   -0.382683432f,-0.471396737f,-0.555570233f,-0.634393284f,
   -0.707106781f,-0.773010453f,-0.831469612f,-0.881921264f,
   -0.923879533f,-0.956940336f,-0.980785280f,-0.995184727f};
__device__ const float TW64S[32] = {
    0.000000000f, 0.098017140f, 0.195090322f, 0.290284677f,
    0.382683432f, 0.471396737f, 0.555570233f, 0.634393284f,
    0.707106781f, 0.773010453f, 0.831469612f, 0.881921264f,
    0.923879533f, 0.956940336f, 0.980785280f, 0.995184727f,
    1.000000000f, 0.995184727f, 0.980785280f, 0.956940336f,
    0.923879533f, 0.881921264f, 0.831469612f, 0.773010453f,
    0.707106781f, 0.634393284f, 0.555570233f, 0.471396737f,
    0.382683432f, 0.290284677f, 0.195090322f, 0.098017140f};

// ---- compile-time step tables: cos/sin(pi*r/(16*DL)) ----
constexpr float KC32[16] = {1.f,0.999981175f,0.999924702f,0.999830582f,0.999698819f,0.999529418f,0.999322385f,0.999077728f,0.998795456f,0.998475581f,0.998118113f,0.997723067f,0.997290457f,0.996820299f,0.996312612f,0.995767414f};
constexpr float KS32[16] = {0.f,0.006135885f,0.012271538f,0.018406730f,0.024541229f,0.030674803f,0.036807223f,0.042938257f,0.049067674f,0.055195244f,0.061320736f,0.067443920f,0.073564564f,0.079682438f,0.085797312f,0.091908956f};
constexpr float KC16[16] = {1.f,0.999924702f,0.999698819f,0.999322385f,0.998795456f,0.998118113f,0.997290457f,0.996312612f,0.995184727f,0.993906970f,0.992479535f,0.990902635f,0.989176510f,0.987301418f,0.985277642f,0.983105487f};
constexpr float KS16[16] = {0.f,0.012271538f,0.024541229f,0.036807223f,0.049067674f,0.061320736f,0.073564564f,0.085797312f,0.098017140f,0.110222207f,0.122410675f,0.134580709f,0.146730474f,0.158858143f,0.170961889f,0.183039888f};
constexpr float KC8[16]  = {1.f,0.999698819f,0.998795456f,0.997290457f,0.995184727f,0.992479535f,0.989176510f,0.985277642f,0.980785280f,0.975702130f,0.970031253f,0.963776066f,0.956940336f,0.949528181f,0.941544065f,0.932992799f};
constexpr float KS8[16]  = {0.f,0.024541229f,0.049067674f,0.073564564f,0.098017140f,0.122410675f,0.146730474f,0.170961889f,0.195090322f,0.219101240f,0.242980180f,0.266712757f,0.290284677f,0.313681740f,0.336889853f,0.359895037f};
constexpr float KC4[16]  = {1.f,0.998795456f,0.995184727f,0.989176510f,0.980785280f,0.970031253f,0.956940336f,0.941544065f,0.923879533f,0.903989293f,0.881921264f,0.857728610f,0.831469612f,0.803207531f,0.773010453f,0.740951125f};
constexpr float KS4[16]  = {0.f,0.049067674f,0.098017140f,0.146730474f,0.195090322f,0.242980180f,0.290284677f,0.336889853f,0.382683432f,0.427555093f,0.471396737f,0.514102744f,0.555570233f,0.595699304f,0.634393284f,0.671558955f};
constexpr float KC2[16]  = {1.f,0.995184727f,0.980785280f,0.956940336f,0.923879533f,0.881921264f,0.831469612f,0.773010453f,0.707106781f,0.634393284f,0.555570233f,0.471396737f,0.382683432f,0.290284677f,0.195090322f,0.098017140f};
constexpr float KS2[16]  = {0.f,0.098017140f,0.195090322f,0.290284677f,0.382683432f,0.471396737f,0.555570233f,0.634393284f,0.707106781f,0.773010453f,0.831469612f,0.881921264f,0.923879533f,0.956940336f,0.980785280f,0.995184727f};
constexpr float KC1[16]  = {1.f,0.980785280f,0.923879533f,0.831469612f,0.707106781f,0.555570233f,0.382683432f,0.195090322f,0.f,-0.195090322f,-0.382683432f,-0.555570233f,-0.707106781f,-0.831469612f,-0.923879533f,-0.980785280f};
constexpr float KS1[16]  = {0.f,0.195090322f,0.382683432f,0.555570233f,0.707106781f,0.831469612f,0.923879533f,0.980785280f,1.f,0.980785280f,0.923879533f,0.831469612f,0.707106781f,0.555570233f,0.382683432f,0.195090322f};

template<int DL, int R>
__host__ __device__ constexpr float TWSTC() {
    if constexpr (DL == 32) return KC32[R];
    else if constexpr (DL == 16) return KC16[R];
    else if constexpr (DL == 8)  return KC8[R];
    else if constexpr (DL == 4)  return KC4[R];
    else if constexpr (DL == 2)  return KC2[R];
    else return KC1[R];
}
template<int DL, int R>
__host__ __device__ constexpr float TWSTS() {
    if constexpr (DL == 32) return KS32[R];
    else if constexpr (DL == 16) return KS16[R];
    else if constexpr (DL == 8)  return KS8[R];
    else if constexpr (DL == 4)  return KS4[R];
    else if constexpr (DL == 2)  return KS2[R];
    else return KS1[R];
}

// in-register stage twiddles
constexpr float CF16R[8] = {1.f, 0.92387953f, 0.70710678f, 0.38268343f, 0.f, -0.38268343f, -0.70710678f, -0.92387953f};
constexpr float CF16I[8] = {0.f, -0.38268343f, -0.70710678f, -0.92387953f, -1.f, -0.92387953f, -0.70710678f, -0.38268343f};
constexpr float CI16I[8] = {0.f, 0.38268343f, 0.70710678f, 0.92387953f, 1.f, 0.92387953f, 0.70710678f, 0.38268343f};
constexpr float CF8R[4]  = {1.f, 0.70710678f, 0.f, -0.70710678f};
constexpr float CF8I[4]  = {0.f, -0.70710678f, -1.f, -0.70710678f};
constexpr float CI8I[4]  = {0.f, 0.70710678f, 1.f, 0.70710678f};

// ---------------- register-resident complex-1024 FFT (per wave) ----------------
// layout: point p = 16*lane + r ; forward DIF natural->bitrev, inverse DIT bitrev->natural
// ALL array indices are macro-expanded literals: a single runtime-indexed access
// demotes the whole array to scratch (rounds 2-5: ~1.1 GB scratch round-trip).

template<int DL>
__device__ __forceinline__ void dif_stage(float (&xr)[16], float (&xi)[16], int lane)
{
    float bcr = 1.f, bss = 0.f;
    if constexpr (DL > 1) {
        const int j = (lane & (DL - 1)) * (32 / DL);
        bcr = TW64C[j];
        bss = TW64S[j];
    }
    const float br_ = bcr, bi_ = -bss;    // forward base: e^{-i pi j/32}
    const bool up = (lane & DL) != 0;
    const float sgn = up ? -1.f : 1.f;
#define DIF_R(R) { \
    constexpr float stc = TWSTC<DL, R>(); \
    constexpr float sts = TWSTS<DL, R>(); \
    const float twr = br_ * stc + bi_ * sts; \
    const float twi = bi_ * stc - br_ * sts; \
    const float pr = __shfl_xor(xr[R], DL, 64); \
    const float pi = __shfl_xor(xi[R], DL, 64); \
    const float tr = fmaf(sgn, xr[R], pr); \
    const float ti = fmaf(sgn, xi[R], pi); \
    const float mr = tr * twr - ti * twi; \
    const float mi = tr * twi + ti * twr; \
    xr[R] = up ? mr : tr; \
    xi[R] = up ? mi : ti; }
    DIF_R(0)  DIF_R(1)  DIF_R(2)  DIF_R(3)  DIF_R(4)  DIF_R(5)  DIF_R(6)  DIF_R(7)
    DIF_R(8)  DIF_R(9)  DIF_R(10) DIF_R(11) DIF_R(12) DIF_R(13) DIF_R(14) DIF_R(15)
#undef DIF_R
}

template<int DL>
__device__ __forceinline__ void dit_stage(float (&xr)[16], float (&xi)[16], int lane)
{
    float bcr = 1.f, bss = 0.f;
    if constexpr (DL > 1) {
        const int j = (lane & (DL - 1)) * (32 / DL);
        bcr = TW64C[j];
        bss = TW64S[j];
    }
    const float br_ = bcr, bi_ = bss;     // inverse base: conjugate
    const bool up = (lane & DL) != 0;
    const float sgn = up ? -1.f : 1.f;
#define DIT_R(R) { \
    constexpr float stc = TWSTC<DL, R>(); \
    constexpr float sts = TWSTS<DL, R>(); \
    const float twr = br_ * stc - bi_ * sts; \
    const float twi = br_ * sts + bi_ * stc; \
    const float pr  = __shfl_xor(xr[R], DL, 64); \
    const float pim = __shfl_xor(xi[R], DL, 64); \
    const float vr = up ? xr[R] : pr; \
    const float vi = up ? xi[R] : pim; \
    const float ur = up ? pr : xr[R]; \
    const float ui = up ? pim : xi[R]; \
    const float cr_ = vr * twr - vi * twi; \
    const float ci_ = vr * twi + vi * twr; \
    xr[R] = fmaf(sgn, cr_, ur); \
    xi[R] = fmaf(sgn, ci_, ui); }
    DIT_R(0)  DIT_R(1)  DIT_R(2)  DIT_R(3)  DIT_R(4)  DIT_R(5)  DIT_R(6)  DIT_R(7)
    DIT_R(8)  DIT_R(9)  DIT_R(10) DIT_R(11) DIT_R(12) DIT_R(13) DIT_R(14) DIT_R(15)
#undef DIT_R
}

__device__ __forceinline__ void fft_inreg_fwd(float (&xr)[16], float (&xi)[16])
{
#define BF16F(J) { \
    constexpr float rc = CF16R[J]; constexpr float ic = CF16I[J]; \
    const float arr = xr[J], aii = xi[J], brr = xr[(J)+8], bii = xi[(J)+8]; \
    const float dr = arr - brr, di = aii - bii; \
    xr[J] = arr + brr; xi[J] = aii + bii; \
    xr[(J)+8] = dr * rc - di * ic; \
    xi[(J)+8] = dr * ic + di * rc; }
    BF16F(0) BF16F(1) BF16F(2) BF16F(3) BF16F(4) BF16F(5) BF16F(6) BF16F(7)
#undef BF16F
#define BF8F(I0, J) { \
    constexpr float rc = CF8R[J]; constexpr float ic = CF8I[J]; \
    const float arr = xr[I0], aii = xi[I0], brr = xr[(I0)+4], bii = xi[(I0)+4]; \
    const float dr = arr - brr, di = aii - bii; \
    xr[I0] = arr + brr; xi[I0] = aii + bii; \
    xr[(I0)+4] = dr * rc - di * ic; \
    xi[(I0)+4] = dr * ic + di * rc; }
    BF8F(0,0) BF8F(1,1) BF8F(2,2) BF8F(3,3) BF8F(8,0) BF8F(9,1) BF8F(10,2) BF8F(11,3)
#undef BF8F
#define BF4F(B) { \
    { const float arr = xr[B], aii = xi[B], brr = xr[(B)+2], bii = xi[(B)+2]; \
      xr[B] = arr + brr; xi[B] = aii + bii; \
      xr[(B)+2] = arr - brr; xi[(B)+2] = aii - bii; } \
    { const float arr = xr[(B)+1], aii = xi[(B)+1], brr = xr[(B)+3], bii = xi[(B)+3]; \
      const float dr = arr - brr, di = aii - bii; \
      xr[(B)+1] = arr + brr; xi[(B)+1] = aii + bii; \
      xr[(B)+3] = di; xi[(B)+3] = -dr; } }
    BF4F(0) BF4F(4) BF4F(8) BF4F(12)
#undef BF4F
#define BF2F(B) { \
    const float arr = xr[B], aii = xi[B], brr = xr[(B)+1], bii = xi[(B)+1]; \
    xr[B] = arr + brr; xi[B] = aii + bii; \
    xr[(B)+1] = arr - brr; xi[(B)+1] = aii - bii; }
    BF2F(0) BF2F(2) BF2F(4) BF2F(6) BF2F(8) BF2F(10) BF2F(12) BF2F(14)
#undef BF2F
}

__device__ __forceinline__ void fft_inreg_inv(float (&xr)[16], float (&xi)[16])
{
#define BI2(B) { \
    const float arr = xr[B], aii = xi[B], brr = xr[(B)+1], bii = xi[(B)+1]; \
    xr[B] = arr + brr; xi[B] = aii + bii; \
    xr[(B)+1] = arr - brr; xi[(B)+1] = aii - bii; }
    BI2(0) BI2(2) BI2(4) BI2(6) BI2(8) BI2(10) BI2(12) BI2(14)
#undef BI2
#define BI4(B) { \
    { const float arr = xr[B], aii = xi[B], trr = xr[(B)+2], tii = xi[(B)+2]; \
      xr[B] = arr + trr; xi[B] = aii + tii; \
      xr[(B)+2] = arr - trr; xi[(B)+2] = aii - tii; } \
    { const float arr = xr[(B)+1], aii = xi[(B)+1], brr = xr[(B)+3], bii = xi[(B)+3]; \
      const float trr = -bii, tii = brr; \
      xr[(B)+1] = arr + trr; xi[(B)+1] = aii + tii; \
      xr[(B)+3] = arr - trr; xi[(B)+3] = aii - tii; } }
    BI4(0) BI4(4) BI4(8) BI4(12)
#undef BI4
#define BI8(I0, J) { \
    constexpr float rc = CF8R[J]; constexpr float ic = CI8I[J]; \
    const float brr = xr[(I0)+4], bii = xi[(I0)+4]; \
    const float trr = brr * rc - bii * ic; \
    const float tii = brr * ic + bii * rc; \
    const float arr = xr[I0], aii = xi[I0]; \
    xr[I0] = arr + trr; xi[I0] = aii + tii; \
    xr[(I0)+4] = arr - trr; xi[(I0)+4] = aii - tii; }
    BI8(0,0) BI8(1,1) BI8(2,2) BI8(3,3) BI8(8,0) BI8(9,1) BI8(10,2) BI8(11,3)
#undef BI8
#define BI16(J) { \
    constexpr float rc = CF16R[J]; constexpr float ic = CI16I[J]; \
    const float brr = xr[(J)+8], bii = xi[(J)+8]; \
    const float trr = brr * rc - bii * ic; \
    const float tii = brr * ic + bii * rc; \
    const float arr = xr[J], aii = xi[J]; \
    xr[J] = arr + trr; xi[J] = aii + tii; \
    xr[(J)+8] = arr - trr; xi[(J)+8] = aii - tii; }
    BI16(0) BI16(1) BI16(2) BI16(3) BI16(4) BI16(5) BI16(6) BI16(7)
#undef BI16
}

__device__ __forceinline__ void fft1024_fwd(float (&xr)[16], float (&xi)[16], int lane)
{
    dif_stage<32>(xr, xi, lane);
    dif_stage<16>(xr, xi, lane);
    dif_stage<8>(xr, xi, lane);
    dif_stage<4>(xr, xi, lane);
    dif_stage<2>(xr, xi, lane);
    dif_stage<1>(xr, xi, lane);
    fft_inreg_fwd(xr, xi);
}

__device__ __forceinline__ void fft1024_inv(float (&xr)[16], float (&xi)[16], int lane)
{
    fft_inreg_inv(xr, xi);
    dit_stage<1>(xr, xi, lane);
    dit_stage<2>(xr, xi, lane);
    dit_stage<4>(xr, xi, lane);
    dit_stage<8>(xr, xi, lane);
    dit_stage<16>(xr, xi, lane);
    dit_stage<32>(xr, xi, lane);
}

// ---------------- Kernel A: FFT autocorrelation ----------------
// grid: (E/16, H, N), block = 512 (8 waves); each block: 16 series of (n,h)
// waves_per_eu(1,2): LDS (139 KB) caps at 1 block/CU = 2 waves/EU; min=1 lifts
// the VGPR budget to the real ceiling instead of the occupancy-heuristic 128.
__global__ __attribute__((amdgpu_waves_per_eu(1, 2))) __launch_bounds__(512)
void fftcorr_kernel(
    const float* __restrict__ q, const float* __restrict__ k,
    float* __restrict__ corr_out, float* __restrict__ ws_mean)
{
    extern __shared__ float lds[];
    float* lq = lds;
    float* lk = lds + 16 * RS;

    const int tid = threadIdx.x;
    const int n = blockIdx.z, h = blockIdx.y, e0 = blockIdx.x * 16;

    // ---- stage q,k: float4 loads (64B coalesced), scalar LDS writes into padded rows
    {
        const int eq = tid & 3;       // which float4 of the 16 e's
        const int trow = tid >> 2;    // 0..127
#pragma unroll
        for (int c = 0; c < 8; ++c) {
            const int t = c * 128 + trow;
            const size_t gbase = ((((size_t)n * L_SEQ + t) * NH + h) * NE) + e0 + 4 * eq;
            const float4 qv = *reinterpret_cast<const float4*>(q + gbase);
            const float4 kv = *reinterpret_cast<const float4*>(k + gbase);
            const int ph = physp(t);
            lq[(4 * eq + 0) * RS + ph] = qv.x;
            lq[(4 * eq + 1) * RS + ph] = qv.y;
            lq[(4 * eq + 2) * RS + ph] = qv.z;
            lq[(4 * eq + 3) * RS + ph] = qv.w;
            lk[(4 * eq + 0) * RS + ph] = kv.x;
            lk[(4 * eq + 1) * RS + ph] = kv.y;
            lk[(4 * eq + 2) * RS + ph] = kv.z;
            lk[(4 * eq + 3) * RS + ph] = kv.w;
        }
    }
    __syncthreads();

    const int lane = tid & 63;
    const int wv = tid >> 6;          // 0..7

#pragma unroll 1
    for (int s = 0; s < 2; ++s) {
        const int e = 2 * wv + s;
        const int row = e * RS + 17 * lane;   // physp(16*lane + r) = 17*lane + r
        float ar[16], ai[16], qi[16];

        // ---- Q forward FFT
#define LDQ(R) { ar[R] = lq[row + R]; ai[R] = 0.f; }
        LDQ(0) LDQ(1) LDQ(2) LDQ(3) LDQ(4) LDQ(5) LDQ(6) LDQ(7)
        LDQ(8) LDQ(9) LDQ(10) LDQ(11) LDQ(12) LDQ(13) LDQ(14) LDQ(15)
#undef LDQ
        fft1024_fwd(ar, ai, lane);

        // park Q.re in the (dead) q LDS row; keep Q.im in regs
#define PARK(R) { lq[row + R] = ar[R]; qi[R] = ai[R]; }
        PARK(0) PARK(1) PARK(2) PARK(3) PARK(4) PARK(5) PARK(6) PARK(7)
        PARK(8) PARK(9) PARK(10) PARK(11) PARK(12) PARK(13) PARK(14) PARK(15)
#undef PARK

        // ---- K forward FFT
#define LDK(R) { ar[R] = lk[row + R]; ai[R] = 0.f; }
        LDK(0) LDK(1) LDK(2) LDK(3) LDK(4) LDK(5) LDK(6) LDK(7)
        LDK(8) LDK(9) LDK(10) LDK(11) LDK(12) LDK(13) LDK(14) LDK(15)
#undef LDK
        fft1024_fwd(ar, ai, lane);

        // ---- S = Q * conj(K) / 1024  (elementwise in bit-reversed order)
#define PROD(R) { \
        const float qr = lq[row + R]; \
        const float sr = qr * ar[R] + qi[R] * ai[R]; \
        const float si = qi[R] * ar[R] - qr * ai[R]; \
        ar[R] = sr * (1.f / 1024.f); \
        ai[R] = si * (1.f / 1024.f); }
        PROD(0) PROD(1) PROD(2) PROD(3) PROD(4) PROD(5) PROD(6) PROD(7)
        PROD(8) PROD(9) PROD(10) PROD(11) PROD(12) PROD(13) PROD(14) PROD(15)
#undef PROD

        fft1024_inv(ar, ai, lane);            // corr (natural order, real)

#define STC(R) { lq[row + R] = ar[R]; }
        STC(0) STC(1) STC(2) STC(3) STC(4) STC(5) STC(6) STC(7)
        STC(8) STC(9) STC(10) STC(11) STC(12) STC(13) STC(14) STC(15)
#undef STC
    }
    __syncthreads();

    // ---- transposed coalesced writeout + per-l mean partials
    {
        const int j = tid & 15;       // e within tile
        const int lr = tid >> 4;      // 0..31
#pragma unroll 1
        for (int c = 0; c < 32; ++c) {
            const int l = c * 32 + lr;
            const float val = lq[j * RS + physp(l)];
            corr_out[((((size_t)n * L_SEQ + l) * NH + h) * NE) + e0 + j] = val;
            float sum = val;
            sum += __shfl_xor(sum, 1, 64);
            sum += __shfl_xor(sum, 2, 64);
            sum += __shfl_xor(sum, 4, 64);
            sum += __shfl_xor(sum, 8, 64);
            if (j == 0) atomicAdd(&ws_mean[n * L_SEQ + l], sum);
        }
    }
}

// ---------------- Kernel B: top-6 lags + per-n softmax ----------------
__global__ __launch_bounds__(1024) void topk_softmax_kernel(
    const float* __restrict__ ws_mean, int* __restrict__ ws_idx,
    float* __restrict__ ws_w)
{
    __shared__ float val[1024];
    __shared__ float rv[1024];
    __shared__ int   ri[1024];
    __shared__ int   sel[TOPK];
    const int tid = threadIdx.x;

    float s = 0.f;
    for (int n = 0; n < NB; ++n) s += ws_mean[n * L_SEQ + tid];
    val[tid] = s;
    __syncthreads();

    for (int kk = 0; kk < TOPK; ++kk) {
        rv[tid] = val[tid];
        ri[tid] = tid;
        __syncthreads();
        for (int off = 512; off > 0; off >>= 1) {
            if (tid < off) {
                const float a = rv[tid], b = rv[tid + off];
                const int ia = ri[tid], ib = ri[tid + off];
                if (b > a || (b == a && ib < ia)) { rv[tid] = b; ri[tid] = ib; }
            }
            __syncthreads();
        }
        if (tid == 0) { sel[kk] = ri[0]; val[ri[0]] = -1e30f; }
        __syncthreads();
    }
    if (tid < TOPK) ws_idx[tid] = sel[tid];

    if (tid < NB) {
        float wv[TOPK];
        float m = -1e30f;
        for (int kk = 0; kk < TOPK; ++kk) {
            wv[kk] = ws_mean[tid * L_SEQ + sel[kk]] * (1.f / (NH * NE));
            m = fmaxf(m, wv[kk]);
        }
        float sum = 0.f;
        for (int kk = 0; kk < TOPK; ++kk) { wv[kk] = expf(wv[kk] - m); sum += wv[kk]; }
        const float inv = 1.f / sum;
        for (int kk = 0; kk < TOPK; ++kk) ws_w[tid * 8 + kk] = wv[kk] * inv;
    }
}

// ---------------- Kernel C: lag-gather weighted sum of v ----------------
__global__ __launch_bounds__(256) void gather_kernel(
    const float* __restrict__ v, const int* __restrict__ ws_idx,
    const float* __restrict__ ws_w, float* __restrict__ out)
{
    const int n = blockIdx.y;
    const int idx4 = blockIdx.x * 256 + threadIdx.x;
    const int l = idx4 >> 7;
    const int r = idx4 & 127;
    const float* wrow = ws_w + n * 8;

    float4 acc = make_float4(0.f, 0.f, 0.f, 0.f);
#pragma unroll
    for (int kk = 0; kk < TOPK; ++kk) {
        const int t = (l + ws_idx[kk]) & (L_SEQ - 1);
        const float4 vv = *reinterpret_cast<const float4*>(
            v + (((size_t)n * L_SEQ + t) * (NH * NE)) + r * 4);
        const float wk = wrow[kk];
        acc.x = fmaf(wk, vv.x, acc.x);
        acc.y = fmaf(wk, vv.y, acc.y);
        acc.z = fmaf(wk, vv.z, acc.z);
        acc.w = fmaf(wk, vv.w, acc.w);
    }
    *reinterpret_cast<float4*>(out + ((size_t)n * L_SEQ + l) * (NH * NE) + r * 4) = acc;
}

extern "C" void kernel_launch(void* const* d_in, const int* in_sizes, int n_in,
                              void* d_out, int out_size, void* d_ws, size_t ws_size,
                              hipStream_t stream)
{
    const float* q = (const float*)d_in[0];
    const float* k = (const float*)d_in[1];
    const float* v = (const float*)d_in[2];
    float* out = (float*)d_out;
    float* corr_out = out + (size_t)NB * L_SEQ * NH * NE;

    float* ws_mean = (float*)d_ws;                              // 32*1024 f32
    int*   ws_idx  = (int*)((char*)d_ws + 131072);              // 6 ints
    float* ws_w    = (float*)((char*)d_ws + 131072 + 256);      // 32*8 f32

    hipMemsetAsync(d_ws, 0, 131072, stream);
    const size_t lds_bytes = (size_t)2 * 16 * RS * sizeof(float);   // 139,392 B
    fftcorr_kernel<<<dim3(NE / 16, NH, NB), 512, lds_bytes, stream>>>(q, k, corr_out, ws_mean);
    topk_softmax_kernel<<<1, 1024, 0, stream>>>(ws_mean, ws_idx, ws_w);
    gather_kernel<<<dim3(512, NB), 256, 0, stream>>>(v, ws_idx, ws_w, out);
}

// Round 7
// 295.469 us; speedup vs baseline: 5.1651x; 5.1651x over previous
//
#include <hip/hip_runtime.h>

#define L_SEQ 1024
#define NB 32
#define NH 8
#define NE 64
#define TOPK 6

// LDS geometry: 16 data planes (8 series x {re,im}) + twiddle table.
// Plane: 1024 floats stored as 64 groups of 16 at stride 20 (16B-aligned
// quads, pad breaks power-of-2 bank strides). Plane stride 1288 floats
// (mod 32 = 8) staggers banks across planes.
#define PS   1288
#define TBO  (16 * PS)            // table offset: TC[272] then TS[272]
#define PHYS(L)  (20 * ((L) >> 4) + ((L) & 15))
#define TPHYS(E) ((E) + ((E) >> 4))
#define LDS_FLOATS (TBO + 544)    // 21152 floats = 84,608 B

// ---------------------------------------------------------------------------
// Radix-4 "double stage" = two fused radix-2 levels (span M, then M/2).
// 256 butterflies/stage; lane (0..63) owns 4 consecutive butterflies whose
// 16 points form 4 contiguous float4 quads per plane. State: named scalars +
// 8 float4 -> structurally spill-proof (rounds 2-6: any 16-deep per-thread
// array form hit ~1.1+ GB scratch regardless of indexing discipline).
// Twiddles: tw1 = W_M^u from 256-entry LDS table; tw2 = tw1*(-i) (free);
// tw3 = W_{M/2}^u = tw1^2 (4 flops). Forward DIF: natural -> bitrev.
// ---------------------------------------------------------------------------
template<int LG>   // M = 4<<LG, butterfly quarter-span = 1<<LG; LG in {2,4,6,8}
__device__ __forceinline__ void dif_dstage(float* __restrict__ pr, float* __restrict__ pi,
                                           const float* __restrict__ tab, int lane)
{
    const int b0 = lane << 2;
    const int u0 = b0 & ((1 << LG) - 1);
    const int Lb = ((b0 >> LG) << (LG + 2)) + u0;
    const int P0 = PHYS(Lb);
    const int P1 = PHYS(Lb + (1 << LG));
    const int P2 = PHYS(Lb + (2 << LG));
    const int P3 = PHYS(Lb + (3 << LG));
    float4 r0 = *(const float4*)(pr + P0), r1 = *(const float4*)(pr + P1);
    float4 r2 = *(const float4*)(pr + P2), r3 = *(const float4*)(pr + P3);
    float4 i0 = *(const float4*)(pi + P0), i1 = *(const float4*)(pi + P1);
    float4 i2 = *(const float4*)(pi + P2), i3 = *(const float4*)(pi + P3);
#define CBTF(CMP, II) { \
    const int e1 = (u0 + II) << (8 - LG); \
    const float w1c = tab[TPHYS(e1)]; \
    const float w1s = tab[272 + TPHYS(e1)]; \
    const float w3c = w1c * w1c - w1s * w1s; \
    const float w3s = 2.f * w1c * w1s; \
    const float t0r = r0.CMP + r2.CMP, t0i = i0.CMP + i2.CMP; \
    const float d2r = r0.CMP - r2.CMP, d2i = i0.CMP - i2.CMP; \
    const float t2r = d2r * w1c + d2i * w1s, t2i = d2i * w1c - d2r * w1s; \
    const float t1r = r1.CMP + r3.CMP, t1i = i1.CMP + i3.CMP; \
    const float d3r = r1.CMP - r3.CMP, d3i = i1.CMP - i3.CMP; \
    const float m3r = d3r * w1c + d3i * w1s, m3i = d3i * w1c - d3r * w1s; \
    const float t3r = m3i, t3i = -m3r; \
    const float a0r = t0r + t1r, a0i = t0i + t1i; \
    const float a1r = t0r - t1r, a1i = t0i - t1i; \
    const float a2r = t2r + t3r, a2i = t2i + t3i; \
    const float a3r = t2r - t3r, a3i = t2i - t3i; \
    r0.CMP = a0r;                     i0.CMP = a0i; \
    r1.CMP = a1r * w3c + a1i * w3s;   i1.CMP = a1i * w3c - a1r * w3s; \
    r2.CMP = a2r;                     i2.CMP = a2i; \
    r3.CMP = a3r * w3c + a3i * w3s;   i3.CMP = a3i * w3c - a3r * w3s; }
    CBTF(x, 0) CBTF(y, 1) CBTF(z, 2) CBTF(w, 3)
#undef CBTF
    *(float4*)(pr + P0) = r0; *(float4*)(pr + P1) = r1;
    *(float4*)(pr + P2) = r2; *(float4*)(pr + P3) = r3;
    *(float4*)(pi + P0) = i0; *(float4*)(pi + P1) = i1;
    *(float4*)(pi + P2) = i2; *(float4*)(pi + P3) = i3;
}

// forward last double-stage (M=4: levels 4,2; trivial twiddles 1 and -i).
// Each quad's components are one complete butterfly.
__device__ __forceinline__ void dif_last(float* __restrict__ pr, float* __restrict__ pi, int lane)
{
    const int Pb = 20 * lane;   // PHYS(16*lane)
#define Q4F(J) { \
    float4 r = *(const float4*)(pr + Pb + 4 * J); \
    float4 m = *(const float4*)(pi + Pb + 4 * J); \
    const float t0r = r.x + r.z, t0i = m.x + m.z; \
    const float t2r = r.x - r.z, t2i = m.x - m.z; \
    const float t1r = r.y + r.w, t1i = m.y + m.w; \
    const float d3r = r.y - r.w, d3i = m.y - m.w; \
    const float t3r = d3i, t3i = -d3r; \
    r.x = t0r + t1r; m.x = t0i + t1i; \
    r.y = t0r - t1r; m.y = t0i - t1i; \
    r.z = t2r + t3r; m.z = t2i + t3i; \
    r.w = t2r - t3r; m.w = t2i - t3i; \
    *(float4*)(pr + Pb + 4 * J) = r; *(float4*)(pi + Pb + 4 * J) = m; }
    Q4F(0) Q4F(1) Q4F(2) Q4F(3)
#undef Q4F
}

// inverse first double-stage (M=4: levels 2,4; conj twiddles 1 and +i)
__device__ __forceinline__ void dit_first(float* __restrict__ pr, float* __restrict__ pi, int lane)
{
    const int Pb = 20 * lane;
#define Q4I(J) { \
    float4 r = *(const float4*)(pr + Pb + 4 * J); \
    float4 m = *(const float4*)(pi + Pb + 4 * J); \
    const float s0r = r.x + r.y, s0i = m.x + m.y; \
    const float s1r = r.x - r.y, s1i = m.x - m.y; \
    const float s2r = r.z + r.w, s2i = m.z + m.w; \
    const float s3r = r.z - r.w, s3i = m.z - m.w; \
    const float p3r = -s3i, p3i = s3r; \
    r.x = s0r + s2r; m.x = s0i + s2i; \
    r.z = s0r - s2r; m.z = s0i - s2i; \
    r.y = s1r + p3r; m.y = s1i + p3i; \
    r.w = s1r - p3r; m.w = s1i - p3i; \
    *(float4*)(pr + Pb + 4 * J) = r; *(float4*)(pi + Pb + 4 * J) = m; }
    Q4I(0) Q4I(1) Q4I(2) Q4I(3)
#undef Q4I
}

// inverse double-stage (levels M/2 then M; conjugate twiddles)
template<int LG>
__device__ __forceinline__ void dit_dstage(float* __restrict__ pr, float* __restrict__ pi,
                                           const float* __restrict__ tab, int lane)
{
    const int b0 = lane << 2;
    const int u0 = b0 & ((1 << LG) - 1);
    const int Lb = ((b0 >> LG) << (LG + 2)) + u0;
    const int P0 = PHYS(Lb);
    const int P1 = PHYS(Lb + (1 << LG));
    const int P2 = PHYS(Lb + (2 << LG));
    const int P3 = PHYS(Lb + (3 << LG));
    float4 r0 = *(const float4*)(pr + P0), r1 = *(const float4*)(pr + P1);
    float4 r2 = *(const float4*)(pr + P2), r3 = *(const float4*)(pr + P3);
    float4 i0 = *(const float4*)(pi + P0), i1 = *(const float4*)(pi + P1);
    float4 i2 = *(const float4*)(pi + P2), i3 = *(const float4*)(pi + P3);
#define CBTI(CMP, II) { \
    const int e1 = (u0 + II) << (8 - LG); \
    const float w1c = tab[TPHYS(e1)]; \
    const float w1s = tab[272 + TPHYS(e1)]; \
    const float w3c = w1c * w1c - w1s * w1s; \
    const float w3s = 2.f * w1c * w1s; \
    const float m1r = r1.CMP * w3c - i1.CMP * w3s, m1i = i1.CMP * w3c + r1.CMP * w3s; \
    const float s0r = r0.CMP + m1r, s0i = i0.CMP + m1i; \
    const float s1r = r0.CMP - m1r, s1i = i0.CMP - m1i; \
    const float m3r = r3.CMP * w3c - i3.CMP * w3s, m3i = i3.CMP * w3c + r3.CMP * w3s; \
    const float s2r = r2.CMP + m3r, s2i = i2.CMP + m3i; \
    const float s3r = r2.CMP - m3r, s3i = i2.CMP - m3i; \
    const float p2r = s2r * w1c - s2i * w1s, p2i = s2i * w1c + s2r * w1s; \
    const float n3r = s3r * w1c - s3i * w1s, n3i = s3i * w1c + s3r * w1s; \
    const float p3r = -n3i, p3i = n3r; \
    r0.CMP = s0r + p2r; i0.CMP = s0i + p2i; \
    r2.CMP = s0r - p2r; i2.CMP = s0i - p2i; \
    r1.CMP = s1r + p3r; i1.CMP = s1i + p3i; \
    r3.CMP = s1r - p3r; i3.CMP = s1i - p3i; }
    CBTI(x, 0) CBTI(y, 1) CBTI(z, 2) CBTI(w, 3)
#undef CBTI
    *(float4*)(pr + P0) = r0; *(float4*)(pr + P1) = r1;
    *(float4*)(pr + P2) = r2; *(float4*)(pr + P3) = r3;
    *(float4*)(pi + P0) = i0; *(float4*)(pi + P1) = i1;
    *(float4*)(pi + P2) = i2; *(float4*)(pi + P3) = i3;
}

// ---------------- Kernel A: FFT autocorrelation (LDS-resident) ----------------
// grid (NE/8, NH, NB), block 256 = 4 waves; 8 series/block, 2 per wave.
// Per series: fwd FFT of z=q+ik -> unpack S=Q*conj(K)/1024 in bitrev domain
// (pair-owner rule p<=pbar; write conj(S) at pbar => exactly-real inverse)
// -> inv FFT -> corr (natural order) in the re-plane. No barriers inside
// (wave-private planes; per-wave DS ordering).
__global__ __launch_bounds__(256) void fftcorr_kernel(
    const float* __restrict__ q, const float* __restrict__ k,
    float* __restrict__ corr_out, float* __restrict__ ws_mean)
{
    extern __shared__ float LDSF[];
    const int tid = threadIdx.x;
    const int n = blockIdx.z, h = blockIdx.y, e0 = blockIdx.x * 8;

    // twiddle table: T[t] = (cos, sin)(2*pi*t/1024), t = 0..255, pad-17 swizzle
    {
        float sv, cv;
        __sincosf((float)tid * (6.2831853071795865f / 1024.f), &sv, &cv);
        LDSF[TBO + TPHYS(tid)] = cv;
        LDSF[TBO + 272 + TPHYS(tid)] = sv;
    }

    // stage: z.re-plane = q, z.im-plane = k (float4 global loads)
    {
        const int quad = tid & 3;
        const int tt  = tid >> 2;          // 0..63
        const int eh  = quad & 1;          // which float4 of the 8 e's
        const int isk = quad >> 1;         // 0 = q -> re, 1 = k -> im
        const float* __restrict__ src = isk ? k : q;
#pragma unroll
        for (int c = 0; c < 16; ++c) {
            const int t = c * 64 + tt;
            const size_t g = ((((size_t)n * L_SEQ + t) * NH + h) * NE) + e0 + 4 * eh;
            const float4 v = *reinterpret_cast<const float4*>(src + g);
            const int ph = PHYS(t);
            LDSF[(size_t)(2 * (4 * eh + 0) + isk) * PS + ph] = v.x;
            LDSF[(size_t)(2 * (4 * eh + 1) + isk) * PS + ph] = v.y;
            LDSF[(size_t)(2 * (4 * eh + 2) + isk) * PS + ph] = v.z;
            LDSF[(size_t)(2 * (4 * eh + 3) + isk) * PS + ph] = v.w;
        }
    }
    __syncthreads();

    const int w = tid >> 6;
    const int lane = tid & 63;
    const float* tab = LDSF + TBO;

#pragma unroll 1
    for (int s = 0; s < 2; ++s) {
        const int e = 2 * w + s;
        float* pr = LDSF + (size_t)(2 * e) * PS;
        float* pi = LDSF + (size_t)(2 * e + 1) * PS;

        // forward DIF: natural -> bitrev
        dif_dstage<8>(pr, pi, tab, lane);
        dif_dstage<6>(pr, pi, tab, lane);
        dif_dstage<4>(pr, pi, tab, lane);
        dif_dstage<2>(pr, pi, tab, lane);
        dif_last(pr, pi, lane);

        // unpack z-spectrum + product, in bitrev domain.
        // Each position read/written only by its pair-owner lane -> race-free.
#pragma unroll 1
        for (int jj = 0; jj < 16; ++jj) {
            const int p  = (lane << 4) + jj;
            const int f  = (int)(__brev((unsigned)p) >> 22);
            const int fb = (1024 - f) & 1023;
            const int pb = (int)(__brev((unsigned)fb) >> 22);
            if (p <= pb) {
                const float ar = pr[PHYS(p)],  ai = pi[PHYS(p)];
                const float br = pr[PHYS(pb)], bi = pi[PHYS(pb)];
                const float Qr = 0.5f * (ar + br), Qi = 0.5f * (ai - bi);
                const float Kr = 0.5f * (ai + bi), Ki = 0.5f * (br - ar);
                const float Sr = (Qr * Kr + Qi * Ki) * (1.f / 1024.f);
                const float Si = (Qi * Kr - Qr * Ki) * (1.f / 1024.f);
                pr[PHYS(p)]  = Sr;  pi[PHYS(p)]  = Si;
                pr[PHYS(pb)] = Sr;  pi[PHYS(pb)] = -Si;
            }
        }

        // inverse DIT: bitrev -> natural; corr lands in re-plane
        dit_first(pr, pi, lane);
        dit_dstage<2>(pr, pi, tab, lane);
        dit_dstage<4>(pr, pi, tab, lane);
        dit_dstage<6>(pr, pi, tab, lane);
        dit_dstage<8>(pr, pi, tab, lane);
    }
    __syncthreads();

    // transposed coalesced writeout + per-l mean partials
    {
        const int j  = tid & 7;        // e within tile
        const int lr = tid >> 3;       // 0..31
#pragma unroll 1
        for (int c = 0; c < 32; ++c) {
            const int l = c * 32 + lr;
            const float val = LDSF[(size_t)(2 * j) * PS + PHYS(l)];
            corr_out[((((size_t)n * L_SEQ + l) * NH + h) * NE) + e0 + j] = val;
            float sum = val;
            sum += __shfl_xor(sum, 1, 64);
            sum += __shfl_xor(sum, 2, 64);
            sum += __shfl_xor(sum, 4, 64);
            if (j == 0) atomicAdd(&ws_mean[n * L_SEQ + l], sum);
        }
    }
}

// ---------------- Kernel B: top-6 lags + per-n softmax ----------------
__global__ __launch_bounds__(1024) void topk_softmax_kernel(
    const float* __restrict__ ws_mean, int* __restrict__ ws_idx,
    float* __restrict__ ws_w)
{
    __shared__ float val[1024];
    __shared__ float rv[1024];
    __shared__ int   ri[1024];
    __shared__ int   sel[TOPK];
    const int tid = threadIdx.x;

    float s = 0.f;
    for (int n = 0; n < NB; ++n) s += ws_mean[n * L_SEQ + tid];
    val[tid] = s;
    __syncthreads();

    for (int kk = 0; kk < TOPK; ++kk) {
        rv[tid] = val[tid];
        ri[tid] = tid;
        __syncthreads();
        for (int off = 512; off > 0; off >>= 1) {
            if (tid < off) {
                const float a = rv[tid], b = rv[tid + off];
                const int ia = ri[tid], ib = ri[tid + off];
                if (b > a || (b == a && ib < ia)) { rv[tid] = b; ri[tid] = ib; }
            }
            __syncthreads();
        }
        if (tid == 0) { sel[kk] = ri[0]; val[ri[0]] = -1e30f; }
        __syncthreads();
    }
    if (tid < TOPK) ws_idx[tid] = sel[tid];

    if (tid < NB) {
        float wv[TOPK];
        float m = -1e30f;
        for (int kk = 0; kk < TOPK; ++kk) {
            wv[kk] = ws_mean[tid * L_SEQ + sel[kk]] * (1.f / (NH * NE));
            m = fmaxf(m, wv[kk]);
        }
        float sum = 0.f;
        for (int kk = 0; kk < TOPK; ++kk) { wv[kk] = expf(wv[kk] - m); sum += wv[kk]; }
        const float inv = 1.f / sum;
        for (int kk = 0; kk < TOPK; ++kk) ws_w[tid * 8 + kk] = wv[kk] * inv;
    }
}

// ---------------- Kernel C: lag-gather weighted sum of v ----------------
__global__ __launch_bounds__(256) void gather_kernel(
    const float* __restrict__ v, const int* __restrict__ ws_idx,
    const float* __restrict__ ws_w, float* __restrict__ out)
{
    const int n = blockIdx.y;
    const int idx4 = blockIdx.x * 256 + threadIdx.x;
    const int l = idx4 >> 7;
    const int r = idx4 & 127;
    const float* wrow = ws_w + n * 8;

    float4 acc = make_float4(0.f, 0.f, 0.f, 0.f);
#pragma unroll
    for (int kk = 0; kk < TOPK; ++kk) {
        const int t = (l + ws_idx[kk]) & (L_SEQ - 1);
        const float4 vv = *reinterpret_cast<const float4*>(
            v + (((size_t)n * L_SEQ + t) * (NH * NE)) + r * 4);
        const float wk = wrow[kk];
        acc.x = fmaf(wk, vv.x, acc.x);
        acc.y = fmaf(wk, vv.y, acc.y);
        acc.z = fmaf(wk, vv.z, acc.z);
        acc.w = fmaf(wk, vv.w, acc.w);
    }
    *reinterpret_cast<float4*>(out + ((size_t)n * L_SEQ + l) * (NH * NE) + r * 4) = acc;
}

extern "C" void kernel_launch(void* const* d_in, const int* in_sizes, int n_in,
                              void* d_out, int out_size, void* d_ws, size_t ws_size,
                              hipStream_t stream)
{
    const float* q = (const float*)d_in[0];
    const float* k = (const float*)d_in[1];
    const float* v = (const float*)d_in[2];
    float* out = (float*)d_out;
    float* corr_out = out + (size_t)NB * L_SEQ * NH * NE;

    float* ws_mean = (float*)d_ws;                              // 32*1024 f32
    int*   ws_idx  = (int*)((char*)d_ws + 131072);              // 6 ints
    float* ws_w    = (float*)((char*)d_ws + 131072 + 256);      // 32*8 f32

    hipMemsetAsync(d_ws, 0, 131072, stream);
    const size_t lds_bytes = (size_t)LDS_FLOATS * sizeof(float);   // 84,608 B
    fftcorr_kernel<<<dim3(NE / 8, NH, NB), 256, lds_bytes, stream>>>(q, k, corr_out, ws_mean);
    topk_softmax_kernel<<<1, 1024, 0, stream>>>(ws_mean, ws_idx, ws_w);
    gather_kernel<<<dim3(512, NB), 256, 0, stream>>>(v, ws_idx, ws_w, out);
}

// Round 8
// 259.434 us; speedup vs baseline: 5.8826x; 1.1389x over previous
//
#include <hip/hip_runtime.h>

#define L_SEQ 1024
#define NB 32
#define NH 8
#define NE 64
#define TOPK 6

// LDS geometry: 16 data planes (8 series x {re,im}) + twiddle table.
// Plane: 1024 floats stored as 64 groups of 16 at stride 20 (16B-aligned
// quads, pad breaks power-of-2 bank strides). Plane stride 1288 floats
// (mod 32 = 8) staggers banks across planes.
#define PS   1288
#define TBO  (16 * PS)            // table offset: TC[272] then TS[272]
#define PHYS(L)  (20 * ((L) >> 4) + ((L) & 15))
#define TPHYS(E) ((E) + ((E) >> 4))
#define LDS_FLOATS (TBO + 544)    // 21152 floats = 84,608 B

// ---------------------------------------------------------------------------
// Radix-4 "double stage" = two fused radix-2 levels (span M, then M/2).
// Named float4/scalar state ONLY: any 16-deep per-thread f32 array form is
// demoted to scratch by this compiler in this kernel shape (rounds 2-6:
// ~1.1-1.5 GB scratch round-trip, invariant under indexing discipline).
// ---------------------------------------------------------------------------
template<int LG>   // M = 4<<LG, butterfly quarter-span = 1<<LG; LG in {2,4,6,8}
__device__ __forceinline__ void dif_dstage(float* __restrict__ pr, float* __restrict__ pi,
                                           const float* __restrict__ tab, int lane)
{
    const int b0 = lane << 2;
    const int u0 = b0 & ((1 << LG) - 1);
    const int Lb = ((b0 >> LG) << (LG + 2)) + u0;
    const int P0 = PHYS(Lb);
    const int P1 = PHYS(Lb + (1 << LG));
    const int P2 = PHYS(Lb + (2 << LG));
    const int P3 = PHYS(Lb + (3 << LG));
    float4 r0 = *(const float4*)(pr + P0), r1 = *(const float4*)(pr + P1);
    float4 r2 = *(const float4*)(pr + P2), r3 = *(const float4*)(pr + P3);
    float4 i0 = *(const float4*)(pi + P0), i1 = *(const float4*)(pi + P1);
    float4 i2 = *(const float4*)(pi + P2), i3 = *(const float4*)(pi + P3);
#define CBTF(CMP, II) { \
    const int e1 = (u0 + II) << (8 - LG); \
    const float w1c = tab[TPHYS(e1)]; \
    const float w1s = tab[272 + TPHYS(e1)]; \
    const float w3c = w1c * w1c - w1s * w1s; \
    const float w3s = 2.f * w1c * w1s; \
    const float t0r = r0.CMP + r2.CMP, t0i = i0.CMP + i2.CMP; \
    const float d2r = r0.CMP - r2.CMP, d2i = i0.CMP - i2.CMP; \
    const float t2r = d2r * w1c + d2i * w1s, t2i = d2i * w1c - d2r * w1s; \
    const float t1r = r1.CMP + r3.CMP, t1i = i1.CMP + i3.CMP; \
    const float d3r = r1.CMP - r3.CMP, d3i = i1.CMP - i3.CMP; \
    const float m3r = d3r * w1c + d3i * w1s, m3i = d3i * w1c - d3r * w1s; \
    const float t3r = m3i, t3i = -m3r; \
    const float a0r = t0r + t1r, a0i = t0i + t1i; \
    const float a1r = t0r - t1r, a1i = t0i - t1i; \
    const float a2r = t2r + t3r, a2i = t2i + t3i; \
    const float a3r = t2r - t3r, a3i = t2i - t3i; \
    r0.CMP = a0r;                     i0.CMP = a0i; \
    r1.CMP = a1r * w3c + a1i * w3s;   i1.CMP = a1i * w3c - a1r * w3s; \
    r2.CMP = a2r;                     i2.CMP = a2i; \
    r3.CMP = a3r * w3c + a3i * w3s;   i3.CMP = a3i * w3c - a3r * w3s; }
    CBTF(x, 0) CBTF(y, 1) CBTF(z, 2) CBTF(w, 3)
#undef CBTF
    *(float4*)(pr + P0) = r0; *(float4*)(pr + P1) = r1;
    *(float4*)(pr + P2) = r2; *(float4*)(pr + P3) = r3;
    *(float4*)(pi + P0) = i0; *(float4*)(pi + P1) = i1;
    *(float4*)(pi + P2) = i2; *(float4*)(pi + P3) = i3;
}

// forward last double-stage (M=4: levels 4,2; trivial twiddles 1 and -i)
__device__ __forceinline__ void dif_last(float* __restrict__ pr, float* __restrict__ pi, int lane)
{
    const int Pb = 20 * lane;   // PHYS(16*lane)
#define Q4F(J) { \
    float4 r = *(const float4*)(pr + Pb + 4 * J); \
    float4 m = *(const float4*)(pi + Pb + 4 * J); \
    const float t0r = r.x + r.z, t0i = m.x + m.z; \
    const float t2r = r.x - r.z, t2i = m.x - m.z; \
    const float t1r = r.y + r.w, t1i = m.y + m.w; \
    const float d3r = r.y - r.w, d3i = m.y - m.w; \
    const float t3r = d3i, t3i = -d3r; \
    r.x = t0r + t1r; m.x = t0i + t1i; \
    r.y = t0r - t1r; m.y = t0i - t1i; \
    r.z = t2r + t3r; m.z = t2i + t3i; \
    r.w = t2r - t3r; m.w = t2i - t3i; \
    *(float4*)(pr + Pb + 4 * J) = r; *(float4*)(pi + Pb + 4 * J) = m; }
    Q4F(0) Q4F(1) Q4F(2) Q4F(3)
#undef Q4F
}

// inverse first double-stage (M=4: levels 2,4; conj twiddles 1 and +i)
__device__ __forceinline__ void dit_first(float* __restrict__ pr, float* __restrict__ pi, int lane)
{
    const int Pb = 20 * lane;
#define Q4I(J) { \
    float4 r = *(const float4*)(pr + Pb + 4 * J); \
    float4 m = *(const float4*)(pi + Pb + 4 * J); \
    const float s0r = r.x + r.y, s0i = m.x + m.y; \
    const float s1r = r.x - r.y, s1i = m.x - m.y; \
    const float s2r = r.z + r.w, s2i = m.z + m.w; \
    const float s3r = r.z - r.w, s3i = m.z - m.w; \
    const float p3r = -s3i, p3i = s3r; \
    r.x = s0r + s2r; m.x = s0i + s2i; \
    r.z = s0r - s2r; m.z = s0i - s2i; \
    r.y = s1r + p3r; m.y = s1i + p3i; \
    r.w = s1r - p3r; m.w = s1i - p3i; \
    *(float4*)(pr + Pb + 4 * J) = r; *(float4*)(pi + Pb + 4 * J) = m; }
    Q4I(0) Q4I(1) Q4I(2) Q4I(3)
#undef Q4I
}

// inverse double-stage (levels M/2 then M; conjugate twiddles)
template<int LG>
__device__ __forceinline__ void dit_dstage(float* __restrict__ pr, float* __restrict__ pi,
                                           const float* __restrict__ tab, int lane)
{
    const int b0 = lane << 2;
    const int u0 = b0 & ((1 << LG) - 1);
    const int Lb = ((b0 >> LG) << (LG + 2)) + u0;
    const int P0 = PHYS(Lb);
    const int P1 = PHYS(Lb + (1 << LG));
    const int P2 = PHYS(Lb + (2 << LG));
    const int P3 = PHYS(Lb + (3 << LG));
    float4 r0 = *(const float4*)(pr + P0), r1 = *(const float4*)(pr + P1);
    float4 r2 = *(const float4*)(pr + P2), r3 = *(const float4*)(pr + P3);
    float4 i0 = *(const float4*)(pi + P0), i1 = *(const float4*)(pi + P1);
    float4 i2 = *(const float4*)(pi + P2), i3 = *(const float4*)(pi + P3);
#define CBTI(CMP, II) { \
    const int e1 = (u0 + II) << (8 - LG); \
    const float w1c = tab[TPHYS(e1)]; \
    const float w1s = tab[272 + TPHYS(e1)]; \
    const float w3c = w1c * w1c - w1s * w1s; \
    const float w3s = 2.f * w1c * w1s; \
    const float m1r = r1.CMP * w3c - i1.CMP * w3s, m1i = i1.CMP * w3c + r1.CMP * w3s; \
    const float s0r = r0.CMP + m1r, s0i = i0.CMP + m1i; \
    const float s1r = r0.CMP - m1r, s1i = i0.CMP - m1i; \
    const float m3r = r3.CMP * w3c - i3.CMP * w3s, m3i = i3.CMP * w3c + r3.CMP * w3s; \
    const float s2r = r2.CMP + m3r, s2i = i2.CMP + m3i; \
    const float s3r = r2.CMP - m3r, s3i = i2.CMP - m3i; \
    const float p2r = s2r * w1c - s2i * w1s, p2i = s2i * w1c + s2r * w1s; \
    const float n3r = s3r * w1c - s3i * w1s, n3i = s3i * w1c + s3r * w1s; \
    const float p3r = -n3i, p3i = n3r; \
    r0.CMP = s0r + p2r; i0.CMP = s0i + p2i; \
    r2.CMP = s0r - p2r; i2.CMP = s0i - p2i; \
    r1.CMP = s1r + p3r; i1.CMP = s1i + p3i; \
    r3.CMP = s1r - p3r; i3.CMP = s1i - p3i; }
    CBTI(x, 0) CBTI(y, 1) CBTI(z, 2) CBTI(w, 3)
#undef CBTI
    *(float4*)(pr + P0) = r0; *(float4*)(pr + P1) = r1;
    *(float4*)(pr + P2) = r2; *(float4*)(pr + P3) = r3;
    *(float4*)(pi + P0) = i0; *(float4*)(pi + P1) = i1;
    *(float4*)(pi + P2) = i2; *(float4*)(pi + P3) = i3;
}

// ---------------- Kernel A: FFT autocorrelation (LDS-resident) ----------------
// grid (NE/8, NH, NB), block 512 = 8 waves; 8 series/block, ONE per wave
// (round 7 had 4 waves x 2 series: 1 wave/SIMD, Occupancy 10.8%, VALUBusy 16%
// -> latency-bound. Same LDS, 8 waves -> 2 waves/SIMD hides the stage chain.)
__global__ __launch_bounds__(512) void fftcorr_kernel(
    const float* __restrict__ q, const float* __restrict__ k,
    float* __restrict__ corr_out, float* __restrict__ ws_mean)
{
    extern __shared__ float LDSF[];
    const int tid = threadIdx.x;
    const int n = blockIdx.z, h = blockIdx.y, e0 = blockIdx.x * 8;

    // twiddle table: T[t] = (cos, sin)(2*pi*t/1024), t = 0..255, pad-17 swizzle
    if (tid < 256) {
        float sv, cv;
        __sincosf((float)tid * (6.2831853071795865f / 1024.f), &sv, &cv);
        LDSF[TBO + TPHYS(tid)] = cv;
        LDSF[TBO + 272 + TPHYS(tid)] = sv;
    }

    // stage: z.re-plane = q, z.im-plane = k (float4 global loads; 4096 total)
    {
#pragma unroll
        for (int c = 0; c < 8; ++c) {
            const int idx = c * 512 + tid;        // 0..4095
            const int isk = idx >> 11;            // 0 = q -> re, 1 = k -> im
            const int rem = idx & 2047;
            const int t  = rem >> 1;
            const int eh = rem & 1;               // which float4 of the 8 e's
            const float* __restrict__ src = isk ? k : q;
            const size_t g = ((((size_t)n * L_SEQ + t) * NH + h) * NE) + e0 + 4 * eh;
            const float4 v = *reinterpret_cast<const float4*>(src + g);
            const int ph = PHYS(t);
            LDSF[(size_t)(2 * (4 * eh + 0) + isk) * PS + ph] = v.x;
            LDSF[(size_t)(2 * (4 * eh + 1) + isk) * PS + ph] = v.y;
            LDSF[(size_t)(2 * (4 * eh + 2) + isk) * PS + ph] = v.z;
            LDSF[(size_t)(2 * (4 * eh + 3) + isk) * PS + ph] = v.w;
        }
    }
    __syncthreads();

    const int w = tid >> 6;
    const int lane = tid & 63;
    const float* tab = LDSF + TBO;

    {
        float* pr = LDSF + (size_t)(2 * w) * PS;
        float* pi = pr + PS;

        // forward DIF: natural -> bitrev
        dif_dstage<8>(pr, pi, tab, lane);
        dif_dstage<6>(pr, pi, tab, lane);
        dif_dstage<4>(pr, pi, tab, lane);
        dif_dstage<2>(pr, pi, tab, lane);
        dif_last(pr, pi, lane);

        // unpack z-spectrum + product S = Q*conj(K)/1024, bitrev domain.
        // v2: own-side 'a' values read as float4 (stride-20 quad pattern is
        // conflict-free for b128); every element written exactly once by its
        // pair-owner (p <= pb) -> race-free, quad reads of non-owned comps unused.
#pragma unroll
        for (int qi = 0; qi < 4; ++qi) {
            const int pbase = (lane << 4) + 4 * qi;
            const int Pq = 20 * lane + 4 * qi;     // PHYS(pbase), quad-aligned
            const float4 ar4 = *(const float4*)(pr + Pq);
            const float4 ai4 = *(const float4*)(pi + Pq);
#define UNP(CMP, JJ) { \
            const int p  = pbase + JJ; \
            const int f  = (int)(__brev((unsigned)p) >> 22); \
            const int fb = (1024 - f) & 1023; \
            const int pb = (int)(__brev((unsigned)fb) >> 22); \
            if (p <= pb) { \
                const float arv = ar4.CMP, aiv = ai4.CMP; \
                const float brv = pr[PHYS(pb)], biv = pi[PHYS(pb)]; \
                const float Qr = 0.5f * (arv + brv), Qi = 0.5f * (aiv - biv); \
                const float Kr = 0.5f * (aiv + biv), Ki = 0.5f * (brv - arv); \
                const float Sr = (Qr * Kr + Qi * Ki) * (1.f / 1024.f); \
                const float Si = (Qi * Kr - Qr * Ki) * (1.f / 1024.f); \
                pr[Pq + JJ] = Sr;   pi[Pq + JJ] = Si; \
                pr[PHYS(pb)] = Sr;  pi[PHYS(pb)] = -Si; \
            } }
            UNP(x, 0) UNP(y, 1) UNP(z, 2) UNP(w, 3)
#undef UNP
        }

        // inverse DIT: bitrev -> natural; corr lands in re-plane
        dit_first(pr, pi, lane);
        dit_dstage<2>(pr, pi, tab, lane);
        dit_dstage<4>(pr, pi, tab, lane);
        dit_dstage<6>(pr, pi, tab, lane);
        dit_dstage<8>(pr, pi, tab, lane);
    }
    __syncthreads();

    // transposed coalesced writeout + per-l mean partials
    {
        const int j  = tid & 7;        // e within tile
        const int lr = tid >> 3;       // 0..63
#pragma unroll 1
        for (int c = 0; c < 16; ++c) {
            const int l = c * 64 + lr;
            const float val = LDSF[(size_t)(2 * j) * PS + PHYS(l)];
            corr_out[((((size_t)n * L_SEQ + l) * NH + h) * NE) + e0 + j] = val;
            float sum = val;
            sum += __shfl_xor(sum, 1, 64);
            sum += __shfl_xor(sum, 2, 64);
            sum += __shfl_xor(sum, 4, 64);
            if (j == 0) atomicAdd(&ws_mean[n * L_SEQ + l], sum);
        }
    }
}

// ---------------- Kernel B: top-6 lags + per-n softmax ----------------
__global__ __launch_bounds__(1024) void topk_softmax_kernel(
    const float* __restrict__ ws_mean, int* __restrict__ ws_idx,
    float* __restrict__ ws_w)
{
    __shared__ float val[1024];
    __shared__ float rv[1024];
    __shared__ int   ri[1024];
    __shared__ int   sel[TOPK];
    const int tid = threadIdx.x;

    float s = 0.f;
    for (int n = 0; n < NB; ++n) s += ws_mean[n * L_SEQ + tid];
    val[tid] = s;
    __syncthreads();

    for (int kk = 0; kk < TOPK; ++kk) {
        rv[tid] = val[tid];
        ri[tid] = tid;
        __syncthreads();
        for (int off = 512; off > 0; off >>= 1) {
            if (tid < off) {
                const float a = rv[tid], b = rv[tid + off];
                const int ia = ri[tid], ib = ri[tid + off];
                if (b > a || (b == a && ib < ia)) { rv[tid] = b; ri[tid] = ib; }
            }
            __syncthreads();
        }
        if (tid == 0) { sel[kk] = ri[0]; val[ri[0]] = -1e30f; }
        __syncthreads();
    }
    if (tid < TOPK) ws_idx[tid] = sel[tid];

    if (tid < NB) {
        float wv[TOPK];
        float m = -1e30f;
        for (int kk = 0; kk < TOPK; ++kk) {
            wv[kk] = ws_mean[tid * L_SEQ + sel[kk]] * (1.f / (NH * NE));
            m = fmaxf(m, wv[kk]);
        }
        float sum = 0.f;
        for (int kk = 0; kk < TOPK; ++kk) { wv[kk] = expf(wv[kk] - m); sum += wv[kk]; }
        const float inv = 1.f / sum;
        for (int kk = 0; kk < TOPK; ++kk) ws_w[tid * 8 + kk] = wv[kk] * inv;
    }
}

// ---------------- Kernel C: lag-gather weighted sum of v ----------------
__global__ __launch_bounds__(256) void gather_kernel(
    const float* __restrict__ v, const int* __restrict__ ws_idx,
    const float* __restrict__ ws_w, float* __restrict__ out)
{
    const int n = blockIdx.y;
    const int idx4 = blockIdx.x * 256 + threadIdx.x;
    const int l = idx4 >> 7;
    const int r = idx4 & 127;
    const float* wrow = ws_w + n * 8;

    float4 acc = make_float4(0.f, 0.f, 0.f, 0.f);
#pragma unroll
    for (int kk = 0; kk < TOPK; ++kk) {
        const int t = (l + ws_idx[kk]) & (L_SEQ - 1);
        const float4 vv = *reinterpret_cast<const float4*>(
            v + (((size_t)n * L_SEQ + t) * (NH * NE)) + r * 4);
        const float wk = wrow[kk];
        acc.x = fmaf(wk, vv.x, acc.x);
        acc.y = fmaf(wk, vv.y, acc.y);
        acc.z = fmaf(wk, vv.z, acc.z);
        acc.w = fmaf(wk, vv.w, acc.w);
    }
    *reinterpret_cast<float4*>(out + ((size_t)n * L_SEQ + l) * (NH * NE) + r * 4) = acc;
}

extern "C" void kernel_launch(void* const* d_in, const int* in_sizes, int n_in,
                              void* d_out, int out_size, void* d_ws, size_t ws_size,
                              hipStream_t stream)
{
    const float* q = (const float*)d_in[0];
    const float* k = (const float*)d_in[1];
    const float* v = (const float*)d_in[2];
    float* out = (float*)d_out;
    float* corr_out = out + (size_t)NB * L_SEQ * NH * NE;

    float* ws_mean = (float*)d_ws;                              // 32*1024 f32
    int*   ws_idx  = (int*)((char*)d_ws + 131072);              // 6 ints
    float* ws_w    = (float*)((char*)d_ws + 131072 + 256);      // 32*8 f32

    hipMemsetAsync(d_ws, 0, 131072, stream);
    const size_t lds_bytes = (size_t)LDS_FLOATS * sizeof(float);   // 84,608 B
    fftcorr_kernel<<<dim3(NE / 8, NH, NB), 512, lds_bytes, stream>>>(q, k, corr_out, ws_mean);
    topk_softmax_kernel<<<1, 1024, 0, stream>>>(ws_mean, ws_idx, ws_w);
    gather_kernel<<<dim3(512, NB), 256, 0, stream>>>(v, ws_idx, ws_w, out);
}

// Round 9
// 193.351 us; speedup vs baseline: 7.8931x; 1.3418x over previous
//
#include <hip/hip_runtime.h>

#define L_SEQ 1024
#define NB 32
#define NH 8
#define NE 64
#define TOPK 6

// LDS geometry: 16 data planes (8 series x {re,im}) + twiddle table.
// Plane: 1024 floats stored as 32 groups of 32 at stride 36 (12.5% pad).
// Hand-checked lane->bank maps: every stage quad pattern (LG=8/6/4/2, last)
// lands exactly 8 lanes/bank (b128 optimum); staging writes 2-way (free).
// 16*1152*4B + table = 75,904 B -> TWO blocks/CU (round 8's 84.6 KB forced 1).
#define PS   1152
#define TBO  (16 * PS)            // table offset: TC[272] then TS[272]
#define PHYS(L)  (36 * ((L) >> 5) + ((L) & 31))
#define TPHYS(E) ((E) + ((E) >> 4))
#define LDS_FLOATS (TBO + 544)    // 18,976 floats = 75,904 B

// ---------------------------------------------------------------------------
// Radix-4 "double stage" = two fused radix-2 levels (span M, then M/2).
// Named float4/scalar state ONLY: any 16-deep per-thread f32 array form is
// demoted to scratch by this compiler in this kernel shape (rounds 2-6:
// ~1.1-1.5 GB scratch round-trip, invariant under indexing discipline).
// ---------------------------------------------------------------------------
template<int LG>   // M = 4<<LG, butterfly quarter-span = 1<<LG; LG in {2,4,6,8}
__device__ __forceinline__ void dif_dstage(float* __restrict__ pr, float* __restrict__ pi,
                                           const float* __restrict__ tab, int lane)
{
    const int b0 = lane << 2;
    const int u0 = b0 & ((1 << LG) - 1);
    const int Lb = ((b0 >> LG) << (LG + 2)) + u0;
    const int P0 = PHYS(Lb);
    const int P1 = PHYS(Lb + (1 << LG));
    const int P2 = PHYS(Lb + (2 << LG));
    const int P3 = PHYS(Lb + (3 << LG));
    float4 r0 = *(const float4*)(pr + P0), r1 = *(const float4*)(pr + P1);
    float4 r2 = *(const float4*)(pr + P2), r3 = *(const float4*)(pr + P3);
    float4 i0 = *(const float4*)(pi + P0), i1 = *(const float4*)(pi + P1);
    float4 i2 = *(const float4*)(pi + P2), i3 = *(const float4*)(pi + P3);
#define CBTF(CMP, II) { \
    const int e1 = (u0 + II) << (8 - LG); \
    const float w1c = tab[TPHYS(e1)]; \
    const float w1s = tab[272 + TPHYS(e1)]; \
    const float w3c = w1c * w1c - w1s * w1s; \
    const float w3s = 2.f * w1c * w1s; \
    const float t0r = r0.CMP + r2.CMP, t0i = i0.CMP + i2.CMP; \
    const float d2r = r0.CMP - r2.CMP, d2i = i0.CMP - i2.CMP; \
    const float t2r = d2r * w1c + d2i * w1s, t2i = d2i * w1c - d2r * w1s; \
    const float t1r = r1.CMP + r3.CMP, t1i = i1.CMP + i3.CMP; \
    const float d3r = r1.CMP - r3.CMP, d3i = i1.CMP - i3.CMP; \
    const float m3r = d3r * w1c + d3i * w1s, m3i = d3i * w1c - d3r * w1s; \
    const float t3r = m3i, t3i = -m3r; \
    const float a0r = t0r + t1r, a0i = t0i + t1i; \
    const float a1r = t0r - t1r, a1i = t0i - t1i; \
    const float a2r = t2r + t3r, a2i = t2i + t3i; \
    const float a3r = t2r - t3r, a3i = t2i - t3i; \
    r0.CMP = a0r;                     i0.CMP = a0i; \
    r1.CMP = a1r * w3c + a1i * w3s;   i1.CMP = a1i * w3c - a1r * w3s; \
    r2.CMP = a2r;                     i2.CMP = a2i; \
    r3.CMP = a3r * w3c + a3i * w3s;   i3.CMP = a3i * w3c - a3r * w3s; }
    CBTF(x, 0) CBTF(y, 1) CBTF(z, 2) CBTF(w, 3)
#undef CBTF
    *(float4*)(pr + P0) = r0; *(float4*)(pr + P1) = r1;
    *(float4*)(pr + P2) = r2; *(float4*)(pr + P3) = r3;
    *(float4*)(pi + P0) = i0; *(float4*)(pi + P1) = i1;
    *(float4*)(pi + P2) = i2; *(float4*)(pi + P3) = i3;
}

// forward last double-stage (M=4: levels 4,2; trivial twiddles 1 and -i)
__device__ __forceinline__ void dif_last(float* __restrict__ pr, float* __restrict__ pi, int lane)
{
    const int Pb = PHYS(lane << 4);   // PHYS(16*lane+4J) = Pb+4J (verified)
#define Q4F(J) { \
    float4 r = *(const float4*)(pr + Pb + 4 * J); \
    float4 m = *(const float4*)(pi + Pb + 4 * J); \
    const float t0r = r.x + r.z, t0i = m.x + m.z; \
    const float t2r = r.x - r.z, t2i = m.x - m.z; \
    const float t1r = r.y + r.w, t1i = m.y + m.w; \
    const float d3r = r.y - r.w, d3i = m.y - m.w; \
    const float t3r = d3i, t3i = -d3r; \
    r.x = t0r + t1r; m.x = t0i + t1i; \
    r.y = t0r - t1r; m.y = t0i - t1i; \
    r.z = t2r + t3r; m.z = t2i + t3i; \
    r.w = t2r - t3r; m.w = t2i - t3i; \
    *(float4*)(pr + Pb + 4 * J) = r; *(float4*)(pi + Pb + 4 * J) = m; }
    Q4F(0) Q4F(1) Q4F(2) Q4F(3)
#undef Q4F
}

// inverse first double-stage (M=4: levels 2,4; conj twiddles 1 and +i)
__device__ __forceinline__ void dit_first(float* __restrict__ pr, float* __restrict__ pi, int lane)
{
    const int Pb = PHYS(lane << 4);
#define Q4I(J) { \
    float4 r = *(const float4*)(pr + Pb + 4 * J); \
    float4 m = *(const float4*)(pi + Pb + 4 * J); \
    const float s0r = r.x + r.y, s0i = m.x + m.y; \
    const float s1r = r.x - r.y, s1i = m.x - m.y; \
    const float s2r = r.z + r.w, s2i = m.z + m.w; \
    const float s3r = r.z - r.w, s3i = m.z - m.w; \
    const float p3r = -s3i, p3i = s3r; \
    r.x = s0r + s2r; m.x = s0i + s2i; \
    r.z = s0r - s2r; m.z = s0i - s2i; \
    r.y = s1r + p3r; m.y = s1i + p3i; \
    r.w = s1r - p3r; m.w = s1i - p3i; \
    *(float4*)(pr + Pb + 4 * J) = r; *(float4*)(pi + Pb + 4 * J) = m; }
    Q4I(0) Q4I(1) Q4I(2) Q4I(3)
#undef Q4I
}

// inverse double-stage (levels M/2 then M; conjugate twiddles)
template<int LG>
__device__ __forceinline__ void dit_dstage(float* __restrict__ pr, float* __restrict__ pi,
                                           const float* __restrict__ tab, int lane)
{
    const int b0 = lane << 2;
    const int u0 = b0 & ((1 << LG) - 1);
    const int Lb = ((b0 >> LG) << (LG + 2)) + u0;
    const int P0 = PHYS(Lb);
    const int P1 = PHYS(Lb + (1 << LG));
    const int P2 = PHYS(Lb + (2 << LG));
    const int P3 = PHYS(Lb + (3 << LG));
    float4 r0 = *(const float4*)(pr + P0), r1 = *(const float4*)(pr + P1);
    float4 r2 = *(const float4*)(pr + P2), r3 = *(const float4*)(pr + P3);
    float4 i0 = *(const float4*)(pi + P0), i1 = *(const float4*)(pi + P1);
    float4 i2 = *(const float4*)(pi + P2), i3 = *(const float4*)(pi + P3);
#define CBTI(CMP, II) { \
    const int e1 = (u0 + II) << (8 - LG); \
    const float w1c = tab[TPHYS(e1)]; \
    const float w1s = tab[272 + TPHYS(e1)]; \
    const float w3c = w1c * w1c - w1s * w1s; \
    const float w3s = 2.f * w1c * w1s; \
    const float m1r = r1.CMP * w3c - i1.CMP * w3s, m1i = i1.CMP * w3c + r1.CMP * w3s; \
    const float s0r = r0.CMP + m1r, s0i = i0.CMP + m1i; \
    const float s1r = r0.CMP - m1r, s1i = i0.CMP - m1i; \
    const float m3r = r3.CMP * w3c - i3.CMP * w3s, m3i = i3.CMP * w3c + r3.CMP * w3s; \
    const float s2r = r2.CMP + m3r, s2i = i2.CMP + m3i; \
    const float s3r = r2.CMP - m3r, s3i = i2.CMP - m3i; \
    const float p2r = s2r * w1c - s2i * w1s, p2i = s2i * w1c + s2r * w1s; \
    const float n3r = s3r * w1c - s3i * w1s, n3i = s3i * w1c + s3r * w1s; \
    const float p3r = -n3i, p3i = n3r; \
    r0.CMP = s0r + p2r; i0.CMP = s0i + p2i; \
    r2.CMP = s0r - p2r; i2.CMP = s0i - p2i; \
    r1.CMP = s1r + p3r; i1.CMP = s1i + p3i; \
    r3.CMP = s1r - p3r; i3.CMP = s1i - p3i; }
    CBTI(x, 0) CBTI(y, 1) CBTI(z, 2) CBTI(w, 3)
#undef CBTI
    *(float4*)(pr + P0) = r0; *(float4*)(pr + P1) = r1;
    *(float4*)(pr + P2) = r2; *(float4*)(pr + P3) = r3;
    *(float4*)(pi + P0) = i0; *(float4*)(pi + P1) = i1;
    *(float4*)(pi + P2) = i2; *(float4*)(pi + P3) = i3;
}

// ---------------- Kernel A: FFT autocorrelation (LDS-resident) ----------------
// grid (NE/8, NH, NB), block 512 = 8 waves; 8 series/block, one per wave.
// 75.9 KB LDS -> 2 blocks/CU = 4 waves/SIMD (round 8: 2/SIMD, latency-bound).
__global__ __launch_bounds__(512) void fftcorr_kernel(
    const float* __restrict__ q, const float* __restrict__ k,
    float* __restrict__ corr_out, float* __restrict__ ws_mean)
{
    extern __shared__ float LDSF[];
    const int tid = threadIdx.x;
    const int n = blockIdx.z, h = blockIdx.y, e0 = blockIdx.x * 8;

    // twiddle table: T[t] = (cos, sin)(2*pi*t/1024), t = 0..255, pad-17 swizzle
    if (tid < 256) {
        float sv, cv;
        __sincosf((float)tid * (6.2831853071795865f / 1024.f), &sv, &cv);
        LDSF[TBO + TPHYS(tid)] = cv;
        LDSF[TBO + 272 + TPHYS(tid)] = sv;
    }

    // stage: z.re-plane = q, z.im-plane = k (float4 global loads; 4096 total)
    {
#pragma unroll
        for (int c = 0; c < 8; ++c) {
            const int idx = c * 512 + tid;        // 0..4095
            const int isk = idx >> 11;            // 0 = q -> re, 1 = k -> im
            const int rem = idx & 2047;
            const int t  = rem >> 1;
            const int eh = rem & 1;               // which float4 of the 8 e's
            const float* __restrict__ src = isk ? k : q;
            const size_t g = ((((size_t)n * L_SEQ + t) * NH + h) * NE) + e0 + 4 * eh;
            const float4 v = *reinterpret_cast<const float4*>(src + g);
            const int ph = PHYS(t);
            LDSF[(size_t)(2 * (4 * eh + 0) + isk) * PS + ph] = v.x;
            LDSF[(size_t)(2 * (4 * eh + 1) + isk) * PS + ph] = v.y;
            LDSF[(size_t)(2 * (4 * eh + 2) + isk) * PS + ph] = v.z;
            LDSF[(size_t)(2 * (4 * eh + 3) + isk) * PS + ph] = v.w;
        }
    }
    __syncthreads();

    const int w = tid >> 6;
    const int lane = tid & 63;
    const float* tab = LDSF + TBO;

    {
        float* pr = LDSF + (size_t)(2 * w) * PS;
        float* pi = pr + PS;

        // forward DIF: natural -> bitrev
        dif_dstage<8>(pr, pi, tab, lane);
        dif_dstage<6>(pr, pi, tab, lane);
        dif_dstage<4>(pr, pi, tab, lane);
        dif_dstage<2>(pr, pi, tab, lane);
        dif_last(pr, pi, lane);

        // unpack z-spectrum + product S = Q*conj(K)/1024, bitrev domain.
        // Own-side reads as float4; every element written exactly once by its
        // pair-owner (p <= pb) -> race-free.
#pragma unroll
        for (int qi = 0; qi < 4; ++qi) {
            const int pbase = (lane << 4) + 4 * qi;
            const int Pq = PHYS(pbase);            // quad-aligned (Pq+JJ valid)
            const float4 ar4 = *(const float4*)(pr + Pq);
            const float4 ai4 = *(const float4*)(pi + Pq);
#define UNP(CMP, JJ) { \
            const int p  = pbase + JJ; \
            const int f  = (int)(__brev((unsigned)p) >> 22); \
            const int fb = (1024 - f) & 1023; \
            const int pb = (int)(__brev((unsigned)fb) >> 22); \
            if (p <= pb) { \
                const float arv = ar4.CMP, aiv = ai4.CMP; \
                const float brv = pr[PHYS(pb)], biv = pi[PHYS(pb)]; \
                const float Qr = 0.5f * (arv + brv), Qi = 0.5f * (aiv - biv); \
                const float Kr = 0.5f * (aiv + biv), Ki = 0.5f * (brv - arv); \
                const float Sr = (Qr * Kr + Qi * Ki) * (1.f / 1024.f); \
                const float Si = (Qi * Kr - Qr * Ki) * (1.f / 1024.f); \
                pr[Pq + JJ] = Sr;   pi[Pq + JJ] = Si; \
                pr[PHYS(pb)] = Sr;  pi[PHYS(pb)] = -Si; \
            } }
            UNP(x, 0) UNP(y, 1) UNP(z, 2) UNP(w, 3)
#undef UNP
        }

        // inverse DIT: bitrev -> natural; corr lands in re-plane
        dit_first(pr, pi, lane);
        dit_dstage<2>(pr, pi, tab, lane);
        dit_dstage<4>(pr, pi, tab, lane);
        dit_dstage<6>(pr, pi, tab, lane);
        dit_dstage<8>(pr, pi, tab, lane);
    }
    __syncthreads();

    // writeout: per-lane float4 across 4 re-planes (bank-spread by l, 2-way
    // free) + 32B-segment global write + pair-shfl mean partial.
    {
#pragma unroll
        for (int c = 0; c < 4; ++c) {
            const int f4idx = c * 512 + tid;     // 0..2047
            const int l  = f4idx >> 1;
            const int j4 = f4idx & 1;            // which float4 of the 8 e's
            const int ph = PHYS(l);
            float4 v;
            v.x = LDSF[(size_t)(2 * (4 * j4 + 0)) * PS + ph];
            v.y = LDSF[(size_t)(2 * (4 * j4 + 1)) * PS + ph];
            v.z = LDSF[(size_t)(2 * (4 * j4 + 2)) * PS + ph];
            v.w = LDSF[(size_t)(2 * (4 * j4 + 3)) * PS + ph];
            *reinterpret_cast<float4*>(
                corr_out + ((((size_t)n * L_SEQ + l) * NH + h) * NE) + e0 + 4 * j4) = v;
            const float esum = v.x + v.y + v.z + v.w;
            const float tot = esum + __shfl_xor(esum, 1, 64);
            if ((tid & 1) == 0) atomicAdd(&ws_mean[n * L_SEQ + l], tot);
        }
    }
}

// ---------------- Kernel B: top-6 lags + per-n softmax ----------------
__global__ __launch_bounds__(1024) void topk_softmax_kernel(
    const float* __restrict__ ws_mean, int* __restrict__ ws_idx,
    float* __restrict__ ws_w)
{
    __shared__ float val[1024];
    __shared__ float rv[1024];
    __shared__ int   ri[1024];
    __shared__ int   sel[TOPK];
    const int tid = threadIdx.x;

    float s = 0.f;
    for (int n = 0; n < NB; ++n) s += ws_mean[n * L_SEQ + tid];
    val[tid] = s;
    __syncthreads();

    for (int kk = 0; kk < TOPK; ++kk) {
        rv[tid] = val[tid];
        ri[tid] = tid;
        __syncthreads();
        for (int off = 512; off > 0; off >>= 1) {
            if (tid < off) {
                const float a = rv[tid], b = rv[tid + off];
                const int ia = ri[tid], ib = ri[tid + off];
                if (b > a || (b == a && ib < ia)) { rv[tid] = b; ri[tid] = ib; }
            }
            __syncthreads();
        }
        if (tid == 0) { sel[kk] = ri[0]; val[ri[0]] = -1e30f; }
        __syncthreads();
    }
    if (tid < TOPK) ws_idx[tid] = sel[tid];

    if (tid < NB) {
        float wv[TOPK];
        float m = -1e30f;
        for (int kk = 0; kk < TOPK; ++kk) {
            wv[kk] = ws_mean[tid * L_SEQ + sel[kk]] * (1.f / (NH * NE));
            m = fmaxf(m, wv[kk]);
        }
        float sum = 0.f;
        for (int kk = 0; kk < TOPK; ++kk) { wv[kk] = expf(wv[kk] - m); sum += wv[kk]; }
        const float inv = 1.f / sum;
        for (int kk = 0; kk < TOPK; ++kk) ws_w[tid * 8 + kk] = wv[kk] * inv;
    }
}

// ---------------- Kernel C: lag-gather weighted sum of v ----------------
__global__ __launch_bounds__(256) void gather_kernel(
    const float* __restrict__ v, const int* __restrict__ ws_idx,
    const float* __restrict__ ws_w, float* __restrict__ out)
{
    const int n = blockIdx.y;
    const int idx4 = blockIdx.x * 256 + threadIdx.x;
    const int l = idx4 >> 7;
    const int r = idx4 & 127;
    const float* wrow = ws_w + n * 8;

    float4 acc = make_float4(0.f, 0.f, 0.f, 0.f);
#pragma unroll
    for (int kk = 0; kk < TOPK; ++kk) {
        const int t = (l + ws_idx[kk]) & (L_SEQ - 1);
        const float4 vv = *reinterpret_cast<const float4*>(
            v + (((size_t)n * L_SEQ + t) * (NH * NE)) + r * 4);
        const float wk = wrow[kk];
        acc.x = fmaf(wk, vv.x, acc.x);
        acc.y = fmaf(wk, vv.y, acc.y);
        acc.z = fmaf(wk, vv.z, acc.z);
        acc.w = fmaf(wk, vv.w, acc.w);
    }
    *reinterpret_cast<float4*>(out + ((size_t)n * L_SEQ + l) * (NH * NE) + r * 4) = acc;
}

extern "C" void kernel_launch(void* const* d_in, const int* in_sizes, int n_in,
                              void* d_out, int out_size, void* d_ws, size_t ws_size,
                              hipStream_t stream)
{
    const float* q = (const float*)d_in[0];
    const float* k = (const float*)d_in[1];
    const float* v = (const float*)d_in[2];
    float* out = (float*)d_out;
    float* corr_out = out + (size_t)NB * L_SEQ * NH * NE;

    float* ws_mean = (float*)d_ws;                              // 32*1024 f32
    int*   ws_idx  = (int*)((char*)d_ws + 131072);              // 6 ints
    float* ws_w    = (float*)((char*)d_ws + 131072 + 256);      // 32*8 f32

    hipMemsetAsync(d_ws, 0, 131072, stream);
    const size_t lds_bytes = (size_t)LDS_FLOATS * sizeof(float);   // 75,904 B
    fftcorr_kernel<<<dim3(NE / 8, NH, NB), 512, lds_bytes, stream>>>(q, k, corr_out, ws_mean);
    topk_softmax_kernel<<<1, 1024, 0, stream>>>(ws_mean, ws_idx, ws_w);
    gather_kernel<<<dim3(512, NB), 256, 0, stream>>>(v, ws_idx, ws_w, out);
}

// Round 10
// 190.134 us; speedup vs baseline: 8.0267x; 1.0169x over previous
//
#include <hip/hip_runtime.h>

#define L_SEQ 1024
#define NB 32
#define NH 8
#define NE 64
#define TOPK 6

// LDS geometry: 16 data planes (8 series x {re,im}) + twiddle table.
// Plane: 1024 floats stored as 32 groups of 32 at stride 36 (12.5% pad).
// 16*1152*4B + table = 75,904 B -> 2 blocks/CU (verified round 9: occ 35.6%).
#define PS   1152
#define TBO  (16 * PS)            // table offset: TC[272] then TS[272]
#define PHYS(L)  (36 * ((L) >> 5) + ((L) & 31))
#define TPHYS(E) ((E) + ((E) >> 4))
#define LDS_FLOATS (TBO + 544)    // 18,976 floats = 75,904 B

// W16^j = (cos(pi j/8), sin(pi j/8)), j = 0..3 (compile-time twiddle steps)
constexpr float K16C[4] = {1.f, 0.92387953f, 0.70710678f, 0.38268343f};
constexpr float K16S[4] = {0.f, 0.38268343f, 0.70710678f, 0.92387953f};

// ---------------------------------------------------------------------------
// Register discipline (rounds 2-7 lesson): named scalars / named float4 ONLY.
// Any 16-deep per-thread f32 array -> demoted to scratch (~1.1-1.5 GB spill).
// All butterflies below are instances of the round-9-verified dstage radix-4
// algebra; twiddles passed as explicit complex values (forward = conj table).
// ---------------------------------------------------------------------------

// radix-4 fused butterfly (two DIF levels M, M/2) on named scalars xr#/xi#.
// Slots (A,B,C,D) at distances (0, D, 2D, 3D); w1 = W_M^{u0}, w3 = w1^2.
#define BTF4F(A,B,C,D) { \
    const float t0r = xr##A + xr##C, t0i = xi##A + xi##C; \
    const float d2r = xr##A - xr##C, d2i = xi##A - xi##C; \
    const float t2r = d2r*w1r - d2i*w1i, t2i = d2i*w1r + d2r*w1i; \
    const float t1r = xr##B + xr##D, t1i = xi##B + xi##D; \
    const float d3r = xr##B - xr##D, d3i = xi##B - xi##D; \
    const float m3r = d3r*w1r - d3i*w1i, m3i = d3i*w1r + d3r*w1i; \
    const float t3r = m3i, t3i = -m3r; \
    const float a0r = t0r + t1r, a0i = t0i + t1i; \
    const float a1r = t0r - t1r, a1i = t0i - t1i; \
    const float a2r = t2r + t3r, a2i = t2i + t3i; \
    const float a3r = t2r - t3r, a3i = t2i - t3i; \
    xr##A = a0r; xi##A = a0i; \
    xr##B = a1r*w3r - a1i*w3i; xi##B = a1i*w3r + a1r*w3i; \
    xr##C = a2r; xi##C = a2i; \
    xr##D = a3r*w3r - a3i*w3i; xi##D = a3i*w3r + a3r*w3i; }

// inverse radix-4 fused (two DIT levels M/2, M), conjugate twiddles in w1/w3.
#define BTF4I(A,B,C,D) { \
    const float m1r = xr##B*w3r - xi##B*w3i, m1i = xi##B*w3r + xr##B*w3i; \
    const float s0r = xr##A + m1r, s0i = xi##A + m1i; \
    const float s1r = xr##A - m1r, s1i = xi##A - m1i; \
    const float m3r = xr##D*w3r - xi##D*w3i, m3i = xi##D*w3r + xr##D*w3i; \
    const float s2r = xr##C + m3r, s2i = xi##C + m3i; \
    const float s3r = xr##C - m3r, s3i = xi##C - m3i; \
    const float t2r = s2r*w1r - s2i*w1i, t2i = s2i*w1r + s2r*w1i; \
    const float n3r = s3r*w1r - s3i*w1i, n3i = s3i*w1r + s3r*w1i; \
    const float t3r = -n3i, t3i = n3r; \
    xr##A = s0r + t2r; xi##A = s0i + t2i; \
    xr##C = s0r - t2r; xi##C = s0i - t2i; \
    xr##B = s1r + t3r; xi##B = s1i + t3i; \
    xr##D = s1r - t3r; xi##D = s1i - t3i; }

// ---- head4: levels 1024,512,256,128 in ONE pass. Lane owns {lane + 64j}.
// PHYS(lane+64j) = A0 + 72j; every scalar op = 2 lanes/bank (free, verified).
__device__ __forceinline__ void head4_fwd(float* __restrict__ pr, float* __restrict__ pi,
                                          const float* __restrict__ tab, int lane)
{
    const int A0 = 36 * (lane >> 5) + (lane & 31);
    const float tc = tab[TPHYS(lane)];
    const float ts = tab[272 + TPHYS(lane)];
    const float wbr = tc, wbi = -ts;                     // W^lane (forward)
    const float w2r = wbr*wbr - wbi*wbi, w2i = 2.f*wbr*wbi;
    const float w4r = w2r*w2r - w2i*w2i, w4i = 2.f*w2r*w2i;
    const float w8r = w4r*w4r - w4i*w4i, w8i = 2.f*w4r*w4i;
#define HD(J) float xr##J = pr[A0 + 72*J]; float xi##J = pi[A0 + 72*J];
    HD(0) HD(1) HD(2) HD(3) HD(4) HD(5) HD(6) HD(7)
    HD(8) HD(9) HD(10) HD(11) HD(12) HD(13) HD(14) HD(15)
#undef HD
    // stage A: M=1024 (levels 1024,512); groups (j, j+4, j+8, j+12); u0 = lane+64j
#define STA(JA,JB,JC,JD,J16) { \
    const float w1r = wbr*K16C[J16] + wbi*K16S[J16]; \
    const float w1i = wbi*K16C[J16] - wbr*K16S[J16]; \
    const float w3r = w1r*w1r - w1i*w1i, w3i = 2.f*w1r*w1i; \
    BTF4F(JA,JB,JC,JD) }
    STA(0,4,8,12,0) STA(1,5,9,13,1) STA(2,6,10,14,2) STA(3,7,11,15,3)
#undef STA
    // stage B: M=256 (levels 256,128); groups (4g..4g+3); u0 = lane -> w1 = wb^4
    {
        const float w1r = w4r, w1i = w4i, w3r = w8r, w3i = w8i;
        BTF4F(0,1,2,3) BTF4F(4,5,6,7) BTF4F(8,9,10,11) BTF4F(12,13,14,15)
    }
#define HS(J) pr[A0 + 72*J] = xr##J; pi[A0 + 72*J] = xi##J;
    HS(0) HS(1) HS(2) HS(3) HS(4) HS(5) HS(6) HS(7)
    HS(8) HS(9) HS(10) HS(11) HS(12) HS(13) HS(14) HS(15)
#undef HS
}

// inverse head4: levels 128,256 then 512,1024 (conjugate twiddles)
__device__ __forceinline__ void head4_inv(float* __restrict__ pr, float* __restrict__ pi,
                                          const float* __restrict__ tab, int lane)
{
    const int A0 = 36 * (lane >> 5) + (lane & 31);
    const float tc = tab[TPHYS(lane)];
    const float ts = tab[272 + TPHYS(lane)];
    const float vbr = tc, vbi = ts;                      // conj(W^lane)
    const float v2r = vbr*vbr - vbi*vbi, v2i = 2.f*vbr*vbi;
    const float v4r = v2r*v2r - v2i*v2i, v4i = 2.f*v2r*v2i;
    const float v8r = v4r*v4r - v4i*v4i, v8i = 2.f*v4r*v4i;
#define HD(J) float xr##J = pr[A0 + 72*J]; float xi##J = pi[A0 + 72*J];
    HD(0) HD(1) HD(2) HD(3) HD(4) HD(5) HD(6) HD(7)
    HD(8) HD(9) HD(10) HD(11) HD(12) HD(13) HD(14) HD(15)
#undef HD
    {   // stage 1: M=256 (levels 128,256)
        const float w1r = v4r, w1i = v4i, w3r = v8r, w3i = v8i;
        BTF4I(0,1,2,3) BTF4I(4,5,6,7) BTF4I(8,9,10,11) BTF4I(12,13,14,15)
    }
    // stage 2: M=1024 (levels 512,1024)
#define STB(JA,JB,JC,JD,J16) { \
    const float w1r = vbr*K16C[J16] - vbi*K16S[J16]; \
    const float w1i = vbi*K16C[J16] + vbr*K16S[J16]; \
    const float w3r = w1r*w1r - w1i*w1i, w3i = 2.f*w1r*w1i; \
    BTF4I(JA,JB,JC,JD) }
    STB(0,4,8,12,0) STB(1,5,9,13,1) STB(2,6,10,14,2) STB(3,7,11,15,3)
#undef STB
#define HS(J) pr[A0 + 72*J] = xr##J; pi[A0 + 72*J] = xi##J;
    HS(0) HS(1) HS(2) HS(3) HS(4) HS(5) HS(6) HS(7)
    HS(8) HS(9) HS(10) HS(11) HS(12) HS(13) HS(14) HS(15)
#undef HS
}

// ---- tail4: levels 16,8,4,2 in ONE pass on the lane's contiguous 16-block.
__device__ __forceinline__ void tail4_fwd(float* __restrict__ pr, float* __restrict__ pi, int lane)
{
    const int Pb = PHYS(lane << 4);
    float4 r0 = *(const float4*)(pr + Pb),      r1 = *(const float4*)(pr + Pb + 4);
    float4 r2 = *(const float4*)(pr + Pb + 8),  r3 = *(const float4*)(pr + Pb + 12);
    float4 i0 = *(const float4*)(pi + Pb),      i1 = *(const float4*)(pi + Pb + 4);
    float4 i2 = *(const float4*)(pi + Pb + 8),  i3 = *(const float4*)(pi + Pb + 12);
    // stage M=16 (levels 16,8): componentwise across quads; u0 = comp
#define TCF(CMP, C) { \
    const float w1r = K16C[C], w1i = -K16S[C]; \
    const float w3r = w1r*w1r - w1i*w1i, w3i = 2.f*w1r*w1i; \
    const float t0r = r0.CMP + r2.CMP, t0i = i0.CMP + i2.CMP; \
    const float d2r = r0.CMP - r2.CMP, d2i = i0.CMP - i2.CMP; \
    const float t2r = d2r*w1r - d2i*w1i, t2i = d2i*w1r + d2r*w1i; \
    const float t1r = r1.CMP + r3.CMP, t1i = i1.CMP + i3.CMP; \
    const float d3r = r1.CMP - r3.CMP, d3i = i1.CMP - i3.CMP; \
    const float m3r = d3r*w1r - d3i*w1i, m3i = d3i*w1r + d3r*w1i; \
    const float t3r = m3i, t3i = -m3r; \
    const float a0r = t0r+t1r, a0i = t0i+t1i; \
    const float a1r = t0r-t1r, a1i = t0i-t1i; \
    const float a2r = t2r+t3r, a2i = t2i+t3i; \
    const float a3r = t2r-t3r, a3i = t2i-t3i; \
    r0.CMP = a0r; i0.CMP = a0i; \
    r1.CMP = a1r*w3r - a1i*w3i; i1.CMP = a1i*w3r + a1r*w3i; \
    r2.CMP = a2r; i2.CMP = a2i; \
    r3.CMP = a3r*w3r - a3i*w3i; i3.CMP = a3i*w3r + a3r*w3i; }
    TCF(x,0) TCF(y,1) TCF(z,2) TCF(w,3)
#undef TCF
    // stage M=4 (levels 4,2) within each quad
#define Q4F(RQ, IQ) { \
    const float t0r = RQ.x + RQ.z, t0i = IQ.x + IQ.z; \
    const float t2r = RQ.x - RQ.z, t2i = IQ.x - IQ.z; \
    const float t1r = RQ.y + RQ.w, t1i = IQ.y + IQ.w; \
    const float d3r = RQ.y - RQ.w, d3i = IQ.y - IQ.w; \
    const float t3r = d3i, t3i = -d3r; \
    RQ.x = t0r + t1r; IQ.x = t0i + t1i; \
    RQ.y = t0r - t1r; IQ.y = t0i - t1i; \
    RQ.z = t2r + t3r; IQ.z = t2i + t3i; \
    RQ.w = t2r - t3r; IQ.w = t2i - t3i; }
    Q4F(r0, i0) Q4F(r1, i1) Q4F(r2, i2) Q4F(r3, i3)
#undef Q4F
    *(float4*)(pr + Pb) = r0;      *(float4*)(pr + Pb + 4) = r1;
    *(float4*)(pr + Pb + 8) = r2;  *(float4*)(pr + Pb + 12) = r3;
    *(float4*)(pi + Pb) = i0;      *(float4*)(pi + Pb + 4) = i1;
    *(float4*)(pi + Pb + 8) = i2;  *(float4*)(pi + Pb + 12) = i3;
}

__device__ __forceinline__ void tail4_inv(float* __restrict__ pr, float* __restrict__ pi, int lane)
{
    const int Pb = PHYS(lane << 4);
    float4 r0 = *(const float4*)(pr + Pb),      r1 = *(const float4*)(pr + Pb + 4);
    float4 r2 = *(const float4*)(pr + Pb + 8),  r3 = *(const float4*)(pr + Pb + 12);
    float4 i0 = *(const float4*)(pi + Pb),      i1 = *(const float4*)(pi + Pb + 4);
    float4 i2 = *(const float4*)(pi + Pb + 8),  i3 = *(const float4*)(pi + Pb + 12);
    // stage M=4 (levels 2,4), conj (+i)
#define Q4I(RQ, IQ) { \
    const float s0r = RQ.x + RQ.y, s0i = IQ.x + IQ.y; \
    const float s1r = RQ.x - RQ.y, s1i = IQ.x - IQ.y; \
    const float s2r = RQ.z + RQ.w, s2i = IQ.z + IQ.w; \
    const float s3r = RQ.z - RQ.w, s3i = IQ.z - IQ.w; \
    const float p3r = -s3i, p3i = s3r; \
    RQ.x = s0r + s2r; IQ.x = s0i + s2i; \
    RQ.z = s0r - s2r; IQ.z = s0i - s2i; \
    RQ.y = s1r + p3r; IQ.y = s1i + p3i; \
    RQ.w = s1r - p3r; IQ.w = s1i - p3i; }
    Q4I(r0, i0) Q4I(r1, i1) Q4I(r2, i2) Q4I(r3, i3)
#undef Q4I
    // stage M=16 (levels 8,16): componentwise, conj twiddles
#define TCI(CMP, C) { \
    const float w1r = K16C[C], w1i = K16S[C]; \
    const float w3r = w1r*w1r - w1i*w1i, w3i = 2.f*w1r*w1i; \
    const float m1r = r1.CMP*w3r - i1.CMP*w3i, m1i = i1.CMP*w3r + r1.CMP*w3i; \
    const float s0r = r0.CMP + m1r, s0i = i0.CMP + m1i; \
    const float s1r = r0.CMP - m1r, s1i = i0.CMP - m1i; \
    const float m3r = r3.CMP*w3r - i3.CMP*w3i, m3i = i3.CMP*w3r + r3.CMP*w3i; \
    const float s2r = r2.CMP + m3r, s2i = i2.CMP + m3i; \
    const float s3r = r2.CMP - m3r, s3i = i2.CMP - m3i; \
    const float t2r = s2r*w1r - s2i*w1i, t2i = s2i*w1r + s2r*w1i; \
    const float n3r = s3r*w1r - s3i*w1i, n3i = s3i*w1r + s3r*w1i; \
    const float t3r = -n3i, t3i = n3r; \
    r0.CMP = s0r + t2r; i0.CMP = s0i + t2i; \
    r2.CMP = s0r - t2r; i2.CMP = s0i - t2i; \
    r1.CMP = s1r + t3r; i1.CMP = s1i + t3i; \
    r3.CMP = s1r - t3r; i3.CMP = s1i - t3i; }
    TCI(x,0) TCI(y,1) TCI(z,2) TCI(w,3)
#undef TCI
    *(float4*)(pr + Pb) = r0;      *(float4*)(pr + Pb + 4) = r1;
    *(float4*)(pr + Pb + 8) = r2;  *(float4*)(pr + Pb + 12) = r3;
    *(float4*)(pi + Pb) = i0;      *(float4*)(pi + Pb + 4) = i1;
    *(float4*)(pi + Pb + 8) = i2;  *(float4*)(pi + Pb + 12) = i3;
}

// ---- mid stage (levels 64,32): unchanged verified round-9 code (LG=4 only)
template<int LG>
__device__ __forceinline__ void dif_dstage(float* __restrict__ pr, float* __restrict__ pi,
                                           const float* __restrict__ tab, int lane)
{
    const int b0 = lane << 2;
    const int u0 = b0 & ((1 << LG) - 1);
    const int Lb = ((b0 >> LG) << (LG + 2)) + u0;
    const int P0 = PHYS(Lb);
    const int P1 = PHYS(Lb + (1 << LG));
    const int P2 = PHYS(Lb + (2 << LG));
    const int P3 = PHYS(Lb + (3 << LG));
    float4 r0 = *(const float4*)(pr + P0), r1 = *(const float4*)(pr + P1);
    float4 r2 = *(const float4*)(pr + P2), r3 = *(const float4*)(pr + P3);
    float4 i0 = *(const float4*)(pi + P0), i1 = *(const float4*)(pi + P1);
    float4 i2 = *(const float4*)(pi + P2), i3 = *(const float4*)(pi + P3);
#define CBTF(CMP, II) { \
    const int e1 = (u0 + II) << (8 - LG); \
    const float w1c = tab[TPHYS(e1)]; \
    const float w1s = tab[272 + TPHYS(e1)]; \
    const float w3c = w1c * w1c - w1s * w1s; \
    const float w3s = 2.f * w1c * w1s; \
    const float t0r = r0.CMP + r2.CMP, t0i = i0.CMP + i2.CMP; \
    const float d2r = r0.CMP - r2.CMP, d2i = i0.CMP - i2.CMP; \
    const float t2r = d2r * w1c + d2i * w1s, t2i = d2i * w1c - d2r * w1s; \
    const float t1r = r1.CMP + r3.CMP, t1i = i1.CMP + i3.CMP; \
    const float d3r = r1.CMP - r3.CMP, d3i = i1.CMP - i3.CMP; \
    const float m3r = d3r * w1c + d3i * w1s, m3i = d3i * w1c - d3r * w1s; \
    const float t3r = m3i, t3i = -m3r; \
    const float a0r = t0r + t1r, a0i = t0i + t1i; \
    const float a1r = t0r - t1r, a1i = t0i - t1i; \
    const float a2r = t2r + t3r, a2i = t2i + t3i; \
    const float a3r = t2r - t3r, a3i = t2i - t3i; \
    r0.CMP = a0r;                     i0.CMP = a0i; \
    r1.CMP = a1r * w3c + a1i * w3s;   i1.CMP = a1i * w3c - a1r * w3s; \
    r2.CMP = a2r;                     i2.CMP = a2i; \
    r3.CMP = a3r * w3c + a3i * w3s;   i3.CMP = a3i * w3c - a3r * w3s; }
    CBTF(x, 0) CBTF(y, 1) CBTF(z, 2) CBTF(w, 3)
#undef CBTF
    *(float4*)(pr + P0) = r0; *(float4*)(pr + P1) = r1;
    *(float4*)(pr + P2) = r2; *(float4*)(pr + P3) = r3;
    *(float4*)(pi + P0) = i0; *(float4*)(pi + P1) = i1;
    *(float4*)(pi + P2) = i2; *(float4*)(pi + P3) = i3;
}

template<int LG>
__device__ __forceinline__ void dit_dstage(float* __restrict__ pr, float* __restrict__ pi,
                                           const float* __restrict__ tab, int lane)
{
    const int b0 = lane << 2;
    const int u0 = b0 & ((1 << LG) - 1);
    const int Lb = ((b0 >> LG) << (LG + 2)) + u0;
    const int P0 = PHYS(Lb);
    const int P1 = PHYS(Lb + (1 << LG));
    const int P2 = PHYS(Lb + (2 << LG));
    const int P3 = PHYS(Lb + (3 << LG));
    float4 r0 = *(const float4*)(pr + P0), r1 = *(const float4*)(pr + P1);
    float4 r2 = *(const float4*)(pr + P2), r3 = *(const float4*)(pr + P3);
    float4 i0 = *(const float4*)(pi + P0), i1 = *(const float4*)(pi + P1);
    float4 i2 = *(const float4*)(pi + P2), i3 = *(const float4*)(pi + P3);
#define CBTI(CMP, II) { \
    const int e1 = (u0 + II) << (8 - LG); \
    const float w1c = tab[TPHYS(e1)]; \
    const float w1s = tab[272 + TPHYS(e1)]; \
    const float w3c = w1c * w1c - w1s * w1s; \
    const float w3s = 2.f * w1c * w1s; \
    const float m1r = r1.CMP * w3c - i1.CMP * w3s, m1i = i1.CMP * w3c + r1.CMP * w3s; \
    const float s0r = r0.CMP + m1r, s0i = i0.CMP + m1i; \
    const float s1r = r0.CMP - m1r, s1i = i0.CMP - m1i; \
    const float m3r = r3.CMP * w3c - i3.CMP * w3s, m3i = i3.CMP * w3c + r3.CMP * w3s; \
    const float s2r = r2.CMP + m3r, s2i = i2.CMP + m3i; \
    const float s3r = r2.CMP - m3r, s3i = i2.CMP - m3i; \
    const float p2r = s2r * w1c - s2i * w1s, p2i = s2i * w1c + s2r * w1s; \
    const float n3r = s3r * w1c - s3i * w1s, n3i = s3i * w1c + s3r * w1s; \
    const float p3r = -n3i, p3i = n3r; \
    r0.CMP = s0r + p2r; i0.CMP = s0i + p2i; \
    r2.CMP = s0r - p2r; i2.CMP = s0i - p2i; \
    r1.CMP = s1r + p3r; i1.CMP = s1i + p3i; \
    r3.CMP = s1r - p3r; i3.CMP = s1i - p3i; }
    CBTI(x, 0) CBTI(y, 1) CBTI(z, 2) CBTI(w, 3)
#undef CBTI
    *(float4*)(pr + P0) = r0; *(float4*)(pr + P1) = r1;
    *(float4*)(pr + P2) = r2; *(float4*)(pr + P3) = r3;
    *(float4*)(pi + P0) = i0; *(float4*)(pi + P1) = i1;
    *(float4*)(pi + P2) = i2; *(float4*)(pi + P3) = i3;
}

// ---------------- Kernel A: FFT autocorrelation (LDS-resident) ----------------
// grid (NE/8, NH, NB), block 512 = 8 waves; 8 series/block, one per wave.
__global__ __launch_bounds__(512) void fftcorr_kernel(
    const float* __restrict__ q, const float* __restrict__ k,
    float* __restrict__ corr_out, float* __restrict__ ws_mean)
{
    extern __shared__ float LDSF[];
    const int tid = threadIdx.x;
    const int n = blockIdx.z, h = blockIdx.y, e0 = blockIdx.x * 8;

    if (tid < 256) {
        float sv, cv;
        __sincosf((float)tid * (6.2831853071795865f / 1024.f), &sv, &cv);
        LDSF[TBO + TPHYS(tid)] = cv;
        LDSF[TBO + 272 + TPHYS(tid)] = sv;
    }

    // stage: z.re-plane = q, z.im-plane = k (float4 global loads; 4096 total)
    {
#pragma unroll
        for (int c = 0; c < 8; ++c) {
            const int idx = c * 512 + tid;
            const int isk = idx >> 11;
            const int rem = idx & 2047;
            const int t  = rem >> 1;
            const int eh = rem & 1;
            const float* __restrict__ src = isk ? k : q;
            const size_t g = ((((size_t)n * L_SEQ + t) * NH + h) * NE) + e0 + 4 * eh;
            const float4 v = *reinterpret_cast<const float4*>(src + g);
            const int ph = PHYS(t);
            LDSF[(size_t)(2 * (4 * eh + 0) + isk) * PS + ph] = v.x;
            LDSF[(size_t)(2 * (4 * eh + 1) + isk) * PS + ph] = v.y;
            LDSF[(size_t)(2 * (4 * eh + 2) + isk) * PS + ph] = v.z;
            LDSF[(size_t)(2 * (4 * eh + 3) + isk) * PS + ph] = v.w;
        }
    }
    __syncthreads();

    const int w = tid >> 6;
    const int lane = tid & 63;
    const float* tab = LDSF + TBO;

    {
        float* pr = LDSF + (size_t)(2 * w) * PS;
        float* pi = pr + PS;

        // forward DIF: 3 passes (1024,512,256,128 | 64,32 | 16,8,4,2)
        head4_fwd(pr, pi, tab, lane);
        dif_dstage<4>(pr, pi, tab, lane);
        tail4_fwd(pr, pi, lane);

        // unpack v3: every position computes its own S = Q*conj(K)/1024 from
        // z(p), z(pb). Arithmetic yields EXACT conjugate pairs -> real inverse.
        // ALL LDS reads (own b128 + partner scalars) precede ALL writes (b128):
        // wave-private series + per-wave DS ordering => race-free.
        const int Pb = PHYS(lane << 4);
        float4 s0r, s0i, s1r, s1i, s2r, s2i, s3r, s3i;
#define UQ(QI) { \
        const float4 a_r = *(const float4*)(pr + Pb + 4*QI); \
        const float4 a_i = *(const float4*)(pi + Pb + 4*QI); \
        UNPC(QI, x, 0) UNPC(QI, y, 1) UNPC(QI, z, 2) UNPC(QI, w, 3) }
#define UNPC(QI, CMP, JJ) { \
        const int p  = (lane << 4) + 4*QI + JJ; \
        const int f  = (int)(__brev((unsigned)p) >> 22); \
        const int fb = (1024 - f) & 1023; \
        const int pb = (int)(__brev((unsigned)fb) >> 22); \
        const int Ppb = PHYS(pb); \
        const float brv = pr[Ppb], biv = pi[Ppb]; \
        const float arv = a_r.CMP, aiv = a_i.CMP; \
        const float Qr = 0.5f*(arv + brv), Qi = 0.5f*(aiv - biv); \
        const float Kr = 0.5f*(aiv + biv), Ki = 0.5f*(brv - arv); \
        s##QI##r.CMP = (Qr*Kr + Qi*Ki) * (1.f/1024.f); \
        s##QI##i.CMP = (Qi*Kr - Qr*Ki) * (1.f/1024.f); }
        UQ(0) UQ(1) UQ(2) UQ(3)
#undef UNPC
#undef UQ
        *(float4*)(pr + Pb)      = s0r;  *(float4*)(pi + Pb)      = s0i;
        *(float4*)(pr + Pb + 4)  = s1r;  *(float4*)(pi + Pb + 4)  = s1i;
        *(float4*)(pr + Pb + 8)  = s2r;  *(float4*)(pi + Pb + 8)  = s2i;
        *(float4*)(pr + Pb + 12) = s3r;  *(float4*)(pi + Pb + 12) = s3i;

        // inverse DIT: 3 passes (2,4,8,16 | 32,64 | 128,256,512,1024)
        tail4_inv(pr, pi, lane);
        dit_dstage<4>(pr, pi, tab, lane);
        head4_inv(pr, pi, tab, lane);
    }
    __syncthreads();

    // writeout: per-lane float4 across 4 re-planes + 32B global write + mean
    {
#pragma unroll
        for (int c = 0; c < 4; ++c) {
            const int f4idx = c * 512 + tid;
            const int l  = f4idx >> 1;
            const int j4 = f4idx & 1;
            const int ph = PHYS(l);
            float4 v;
            v.x = LDSF[(size_t)(2 * (4 * j4 + 0)) * PS + ph];
            v.y = LDSF[(size_t)(2 * (4 * j4 + 1)) * PS + ph];
            v.z = LDSF[(size_t)(2 * (4 * j4 + 2)) * PS + ph];
            v.w = LDSF[(size_t)(2 * (4 * j4 + 3)) * PS + ph];
            *reinterpret_cast<float4*>(
                corr_out + ((((size_t)n * L_SEQ + l) * NH + h) * NE) + e0 + 4 * j4) = v;
            const float esum = v.x + v.y + v.z + v.w;
            const float tot = esum + __shfl_xor(esum, 1, 64);
            if ((tid & 1) == 0) atomicAdd(&ws_mean[n * L_SEQ + l], tot);
        }
    }
}

// ---------------- Kernel B: top-6 lags + per-n softmax ----------------
__global__ __launch_bounds__(1024) void topk_softmax_kernel(
    const float* __restrict__ ws_mean, int* __restrict__ ws_idx,
    float* __restrict__ ws_w)
{
    __shared__ float val[1024];
    __shared__ float rv[1024];
    __shared__ int   ri[1024];
    __shared__ int   sel[TOPK];
    const int tid = threadIdx.x;

    float s = 0.f;
    for (int n = 0; n < NB; ++n) s += ws_mean[n * L_SEQ + tid];
    val[tid] = s;
    __syncthreads();

    for (int kk = 0; kk < TOPK; ++kk) {
        rv[tid] = val[tid];
        ri[tid] = tid;
        __syncthreads();
        for (int off = 512; off > 0; off >>= 1) {
            if (tid < off) {
                const float a = rv[tid], b = rv[tid + off];
                const int ia = ri[tid], ib = ri[tid + off];
                if (b > a || (b == a && ib < ia)) { rv[tid] = b; ri[tid] = ib; }
            }
            __syncthreads();
        }
        if (tid == 0) { sel[kk] = ri[0]; val[ri[0]] = -1e30f; }
        __syncthreads();
    }
    if (tid < TOPK) ws_idx[tid] = sel[tid];

    if (tid < NB) {
        float wv[TOPK];
        float m = -1e30f;
        for (int kk = 0; kk < TOPK; ++kk) {
            wv[kk] = ws_mean[tid * L_SEQ + sel[kk]] * (1.f / (NH * NE));
            m = fmaxf(m, wv[kk]);
        }
        float sum = 0.f;
        for (int kk = 0; kk < TOPK; ++kk) { wv[kk] = expf(wv[kk] - m); sum += wv[kk]; }
        const float inv = 1.f / sum;
        for (int kk = 0; kk < TOPK; ++kk) ws_w[tid * 8 + kk] = wv[kk] * inv;
    }
}

// ---------------- Kernel C: lag-gather weighted sum of v ----------------
__global__ __launch_bounds__(256) void gather_kernel(
    const float* __restrict__ v, const int* __restrict__ ws_idx,
    const float* __restrict__ ws_w, float* __restrict__ out)
{
    const int n = blockIdx.y;
    const int idx4 = blockIdx.x * 256 + threadIdx.x;
    const int l = idx4 >> 7;
    const int r = idx4 & 127;
    const float* wrow = ws_w + n * 8;

    float4 acc = make_float4(0.f, 0.f, 0.f, 0.f);
#pragma unroll
    for (int kk = 0; kk < TOPK; ++kk) {
        const int t = (l + ws_idx[kk]) & (L_SEQ - 1);
        const float4 vv = *reinterpret_cast<const float4*>(
            v + (((size_t)n * L_SEQ + t) * (NH * NE)) + r * 4);
        const float wk = wrow[kk];
        acc.x = fmaf(wk, vv.x, acc.x);
        acc.y = fmaf(wk, vv.y, acc.y);
        acc.z = fmaf(wk, vv.z, acc.z);
        acc.w = fmaf(wk, vv.w, acc.w);
    }
    *reinterpret_cast<float4*>(out + ((size_t)n * L_SEQ + l) * (NH * NE) + r * 4) = acc;
}

extern "C" void kernel_launch(void* const* d_in, const int* in_sizes, int n_in,
                              void* d_out, int out_size, void* d_ws, size_t ws_size,
                              hipStream_t stream)
{
    const float* q = (const float*)d_in[0];
    const float* k = (const float*)d_in[1];
    const float* v = (const float*)d_in[2];
    float* out = (float*)d_out;
    float* corr_out = out + (size_t)NB * L_SEQ * NH * NE;

    float* ws_mean = (float*)d_ws;                              // 32*1024 f32
    int*   ws_idx  = (int*)((char*)d_ws + 131072);              // 6 ints
    float* ws_w    = (float*)((char*)d_ws + 131072 + 256);      // 32*8 f32

    hipMemsetAsync(d_ws, 0, 131072, stream);
    const size_t lds_bytes = (size_t)LDS_FLOATS * sizeof(float);   // 75,904 B
    fftcorr_kernel<<<dim3(NE / 8, NH, NB), 512, lds_bytes, stream>>>(q, k, corr_out, ws_mean);
    topk_softmax_kernel<<<1, 1024, 0, stream>>>(ws_mean, ws_idx, ws_w);
    gather_kernel<<<dim3(512, NB), 256, 0, stream>>>(v, ws_idx, ws_w, out);
}